// Round 3
// baseline (885.668 us; speedup 1.0000x reference)
//
#include <hip/hip_runtime.h>

// ---------------------------------------------------------------------------
// GIN forward on MI355X.
// CSR build (bucketed 2-pass sort) -> [agg (ILP gather) -> GEMM bf16x3] x3 -> head.
// ---------------------------------------------------------------------------

constexpr int NN  = 100000;   // nodes
constexpr int NE  = 1600000;  // edges
constexpr int DIN = 64;
constexpr int HID = 128;
constexpr int NPB   = 98;     // nodes per bucket
constexpr int NBUCK = 1024;   // NPB*NBUCK >= NN

typedef __attribute__((ext_vector_type(4))) float f32x4;
typedef __attribute__((ext_vector_type(8))) short bf16x8;

__device__ __forceinline__ short f2bf(float f) {
    union { float f; unsigned u; } x; x.f = f;
    unsigned r = x.u + 0x7fffu + ((x.u >> 16) & 1u);   // RNE
    return (short)(r >> 16);
}
__device__ __forceinline__ float bf2f(short s) {
    union { unsigned u; float f; } x; x.u = ((unsigned)(unsigned short)s) << 16;
    return x.f;
}

// ---------------------------------------------------------------- CSR build
__global__ void hist_kernel(const int* __restrict__ eidx, int* __restrict__ deg) {
    int e = blockIdx.x * 256 + threadIdx.x;
    if (e < NE) atomicAdd(&deg[eidx[NE + e]], 1);
}

__global__ void scan1_kernel(const int* __restrict__ deg, int* __restrict__ offs,
                             int* __restrict__ bsum) {
    __shared__ int lds[512];
    int t = threadIdx.x;
    int i = blockIdx.x * 512 + t;
    int v = (i < NN) ? deg[i] : 0;
    lds[t] = v; __syncthreads();
    #pragma unroll
    for (int o = 1; o < 512; o <<= 1) {
        int x = (t >= o) ? lds[t - o] : 0;
        __syncthreads();
        lds[t] += x;
        __syncthreads();
    }
    if (i < NN) offs[i] = lds[t] - v;          // exclusive
    if (t == 511) bsum[blockIdx.x] = lds[511]; // block total
}

__global__ void scan2_kernel(int* __restrict__ bsum, int nb) {
    __shared__ int lds[256];
    int t = threadIdx.x;
    int v = (t < nb) ? bsum[t] : 0;
    lds[t] = v; __syncthreads();
    #pragma unroll
    for (int o = 1; o < 256; o <<= 1) {
        int x = (t >= o) ? lds[t - o] : 0;
        __syncthreads();
        lds[t] += x;
        __syncthreads();
    }
    if (t < nb) bsum[t] = lds[t] - v;          // exclusive block base
}

__global__ void scan3_kernel(int* __restrict__ offs, const int* __restrict__ bsum,
                             int* __restrict__ cursor) {
    int i = blockIdx.x * 512 + threadIdx.x;
    if (i < NN) {
        int val = offs[i] + bsum[blockIdx.x];
        offs[i] = val;
        cursor[i] = val;
    }
    if (i == 0) offs[NN] = NE;
}

__global__ void initbcur_kernel(const int* __restrict__ offs, int* __restrict__ bcur) {
    int b = blockIdx.x * 256 + threadIdx.x;
    if (b < NBUCK) {
        int n = b * NPB; if (n > NN) n = NN;
        bcur[b] = offs[n];
    }
}

// pass A: bucket edges by dst/NPB into contiguous bucket regions of tmp
__global__ void bucket_kernel(const int* __restrict__ eidx, int* __restrict__ bcur,
                              int2* __restrict__ tmp) {
    int e = blockIdx.x * 256 + threadIdx.x;
    if (e < NE) {
        int s = eidx[e];
        int d = eidx[NE + e];
        int p = atomicAdd(&bcur[d / NPB], 1);
        tmp[p] = int2{s, d};
    }
}

// pass B: one block per bucket, place edges into final CSR slots (local writes)
__global__ __launch_bounds__(256)
void place_kernel(const int* __restrict__ offs, const int2* __restrict__ tmp,
                  int* __restrict__ cursor, int* __restrict__ esrc) {
    int b = blockIdx.x;
    int n0 = b * NPB;       if (n0 > NN) n0 = NN;
    int n1 = (b + 1) * NPB; if (n1 > NN) n1 = NN;
    int lo = offs[n0], hi = offs[n1];
    for (int i = lo + threadIdx.x; i < hi; i += 256) {
        int2 e = tmp[i];
        int p = atomicAdd(&cursor[e.y], 1);
        esrc[p] = e.x;
    }
}

// ---------------------------------------------------------------- aggregation
// out[n] = (1+eps)*h[n] + sum_{s in nbr(n)} h[s]   (D = 64 or 128, fp32)
// 8-deep unrolled gather for memory-level parallelism.
template<int D>
__global__ __launch_bounds__(256)
void agg_kernel(const float* __restrict__ h, const int* __restrict__ offs,
                const int* __restrict__ esrc, const float* __restrict__ epsp,
                float* __restrict__ out) {
    constexpr int TPN = D / 4;                 // threads per node (float4 lanes)
    int node = blockIdx.x * (256 / TPN) + threadIdx.x / TPN;
    int f4   = threadIdx.x % TPN;
    if (node >= NN) return;
    const f32x4* h4 = (const f32x4*)h;
    float eps = 1.0f + *epsp;
    int k  = offs[node];
    int k1 = offs[node + 1];
    f32x4 a0 = h4[(size_t)node * TPN + f4] * eps;
    f32x4 a1 = (f32x4)0.f, a2 = (f32x4)0.f, a3 = (f32x4)0.f;
    for (; k + 8 <= k1; k += 8) {
        int s0 = esrc[k+0], s1 = esrc[k+1], s2 = esrc[k+2], s3 = esrc[k+3];
        int s4 = esrc[k+4], s5 = esrc[k+5], s6 = esrc[k+6], s7 = esrc[k+7];
        f32x4 t0 = h4[(size_t)s0*TPN+f4], t1 = h4[(size_t)s1*TPN+f4];
        f32x4 t2 = h4[(size_t)s2*TPN+f4], t3 = h4[(size_t)s3*TPN+f4];
        f32x4 t4 = h4[(size_t)s4*TPN+f4], t5 = h4[(size_t)s5*TPN+f4];
        f32x4 t6 = h4[(size_t)s6*TPN+f4], t7 = h4[(size_t)s7*TPN+f4];
        a0 += t0; a1 += t1; a2 += t2; a3 += t3;
        a0 += t4; a1 += t5; a2 += t6; a3 += t7;
    }
    for (; k + 2 <= k1; k += 2) {
        f32x4 t0 = h4[(size_t)esrc[k]*TPN+f4];
        f32x4 t1 = h4[(size_t)esrc[k+1]*TPN+f4];
        a0 += t0; a1 += t1;
    }
    if (k < k1) a2 += h4[(size_t)esrc[k]*TPN+f4];
    ((f32x4*)out)[(size_t)node * TPN + f4] = (a0 + a1) + (a2 + a3);
}

// ---------------------------------------------------------------- weight pack
// All 6 weight matrices in one launch. Pack W[K][128] (fp32) into B-fragment
// order for mfma_f32_16x16x32_bf16, split hi/lo halves.
// frag: P[c][nt][lane][j] = bf16( W[c*32 + (lane>>4)*8 + j][nt*16 + (lane&15)] )
__global__ void packall_kernel(const float* __restrict__ W1a, const float* __restrict__ W1b,
                               const float* __restrict__ W2a, const float* __restrict__ W3a,
                               const float* __restrict__ W3b, const float* __restrict__ Wl,
                               short* P1a, short* P1b, short* P2a,
                               short* P3a, short* P3b, short* Pl) {
    const float* W; short* P; int K;
    switch (blockIdx.y) {
        case 0: W = W1a; P = P1a; K = 64;  break;
        case 1: W = W1b; P = P1b; K = 128; break;
        case 2: W = W2a; P = P2a; K = 128; break;
        case 3: W = W3a; P = P3a; K = 128; break;
        case 4: W = W3b; P = P3b; K = 128; break;
        default: W = Wl; P = Pl;  K = 128; break;
    }
    int T = (K / 32) * 8 * 64;
    int idx = blockIdx.x * 256 + threadIdx.x;
    if (idx >= T) return;
    int c  = idx >> 9;
    int nt = (idx >> 6) & 7;
    int l  = idx & 63;
    int col   = nt * 16 + (l & 15);
    int kbase = c * 32 + (l >> 4) * 8;
    bf16x8 hi, lo;
    #pragma unroll
    for (int j = 0; j < 8; ++j) {
        float w = W[(kbase + j) * HID + col];
        short h = f2bf(w);
        hi[j] = h;
        lo[j] = f2bf(w - bf2f(h));
    }
    *(bf16x8*)&P[(size_t)idx * 8]       = hi;
    *(bf16x8*)&P[(size_t)(T + idx) * 8] = lo;
}

// ---------------------------------------------------------------- GEMM
// C[M,128] = epilogue(A[M,K] @ W[K,128])   via bf16x3 split products.
// 512 threads, 128 rows/block (wave w owns rows 16w..16w+15).
// MODE 0: relu(.+bias)          -> out[M,128]
// MODE 1: bn(relu(.+bias))      -> out[M,128]
// MODE 2: head: dot(relu(.+bias), Wf) + bf -> out[M]
template<int K, int MODE>
__global__ __launch_bounds__(512)
void gemm_kernel(const float* __restrict__ A, const short* __restrict__ P,
                 const float* __restrict__ bias,
                 const float* __restrict__ g, const float* __restrict__ be,
                 const float* __restrict__ m, const float* __restrict__ v,
                 const float* __restrict__ Wf, const float* __restrict__ bf,
                 float* __restrict__ out, int M) {
    constexpr int NCH = K / 32;
    constexpr int T   = NCH * 8 * 64;          // frags per half (hi or lo)
    __shared__ short wlds[2 * T * 8];

    const int tid  = threadIdx.x;
    const int wid  = tid >> 6;
    const int lane = tid & 63;

    // stage packed W (hi then lo) to LDS, linear coalesced 16B
    for (int i = tid; i < 2 * T; i += 512)
        ((bf16x8*)wlds)[i] = ((const bf16x8*)P)[i];
    __syncthreads();

    const int rlo  = lane & 15;
    const int kgrp = lane >> 4;
    const int row  = blockIdx.x * 128 + wid * 16 + rlo;
    const int r    = row < M ? row : M - 1;
    const float* arow = A + (size_t)r * K + kgrp * 8;

    f32x4 acc[8];
    #pragma unroll
    for (int i = 0; i < 8; ++i) acc[i] = (f32x4)0.0f;

    #pragma unroll
    for (int c = 0; c < NCH; ++c) {
        f32x4 a0 = *(const f32x4*)(arow + c * 32);
        f32x4 a1 = *(const f32x4*)(arow + c * 32 + 4);
        bf16x8 ah, al;
        #pragma unroll
        for (int j = 0; j < 4; ++j) {
            short h0 = f2bf(a0[j]);
            short h1 = f2bf(a1[j]);
            ah[j]     = h0;
            ah[j + 4] = h1;
            al[j]     = f2bf(a0[j] - bf2f(h0));
            al[j + 4] = f2bf(a1[j] - bf2f(h1));
        }
        #pragma unroll
        for (int nt = 0; nt < 8; ++nt) {
            int fi = ((c * 8) + nt) * 64 + lane;
            bf16x8 wh = *(bf16x8*)&wlds[(size_t)fi * 8];
            bf16x8 wl = *(bf16x8*)&wlds[(size_t)(T + fi) * 8];
            acc[nt] = __builtin_amdgcn_mfma_f32_16x16x32_bf16(ah, wh, acc[nt], 0, 0, 0);
            acc[nt] = __builtin_amdgcn_mfma_f32_16x16x32_bf16(al, wh, acc[nt], 0, 0, 0);
            acc[nt] = __builtin_amdgcn_mfma_f32_16x16x32_bf16(ah, wl, acc[nt], 0, 0, 0);
        }
    }

    if constexpr (MODE == 2) {
        float p0 = 0, p1 = 0, p2 = 0, p3 = 0;
        #pragma unroll
        for (int nt = 0; nt < 8; ++nt) {
            int col  = nt * 16 + (lane & 15);
            float bb = bias[col];
            float wv = Wf[col];
            p0 += fmaxf(acc[nt][0] + bb, 0.f) * wv;
            p1 += fmaxf(acc[nt][1] + bb, 0.f) * wv;
            p2 += fmaxf(acc[nt][2] + bb, 0.f) * wv;
            p3 += fmaxf(acc[nt][3] + bb, 0.f) * wv;
        }
        #pragma unroll
        for (int o = 1; o < 16; o <<= 1) {
            p0 += __shfl_xor(p0, o);
            p1 += __shfl_xor(p1, o);
            p2 += __shfl_xor(p2, o);
            p3 += __shfl_xor(p3, o);
        }
        if ((lane & 15) == 0) {
            int rbase = blockIdx.x * 128 + wid * 16 + kgrp * 4;
            float bfv = bf[0];
            if (rbase + 0 < M) out[rbase + 0] = p0 + bfv;
            if (rbase + 1 < M) out[rbase + 1] = p1 + bfv;
            if (rbase + 2 < M) out[rbase + 2] = p2 + bfv;
            if (rbase + 3 < M) out[rbase + 3] = p3 + bfv;
        }
    } else {
        #pragma unroll
        for (int nt = 0; nt < 8; ++nt) {
            int col  = nt * 16 + (lane & 15);
            float bb = bias[col];
            float s = 1.f, t = 0.f;
            if constexpr (MODE == 1) {
                float sv = g[col] * rsqrtf(v[col] + 1e-5f);
                s = sv; t = be[col] - m[col] * sv;
            }
            #pragma unroll
            for (int jj = 0; jj < 4; ++jj) {
                int rr = blockIdx.x * 128 + wid * 16 + kgrp * 4 + jj;
                float val = fmaxf(acc[nt][jj] + bb, 0.f);
                if constexpr (MODE == 1) val = val * s + t;
                if (rr < M) out[(size_t)rr * 128 + col] = val;
            }
        }
    }
}

// ---------------------------------------------------------------------------
extern "C" void kernel_launch(void* const* d_in, const int* in_sizes, int n_in,
                              void* d_out, int out_size, void* d_ws, size_t ws_size,
                              hipStream_t stream) {
    const float* x    = (const float*)d_in[0];
    const int*   eidx = (const int*)d_in[1];
    const float* eps1 = (const float*)d_in[2];
    const float* W1a  = (const float*)d_in[3];
    const float* b1a  = (const float*)d_in[4];
    const float* W1b  = (const float*)d_in[5];
    const float* b1b  = (const float*)d_in[6];
    const float* g1   = (const float*)d_in[7];
    const float* be1  = (const float*)d_in[8];
    const float* m1   = (const float*)d_in[9];
    const float* v1   = (const float*)d_in[10];
    const float* eps2 = (const float*)d_in[11];
    const float* W2a  = (const float*)d_in[12];
    const float* b2a  = (const float*)d_in[13];
    const float* g2   = (const float*)d_in[14];
    const float* be2  = (const float*)d_in[15];
    const float* m2   = (const float*)d_in[16];
    const float* v2   = (const float*)d_in[17];
    const float* eps3 = (const float*)d_in[18];
    const float* W3a  = (const float*)d_in[19];
    const float* b3a  = (const float*)d_in[20];
    const float* W3b  = (const float*)d_in[21];
    const float* b3b  = (const float*)d_in[22];
    const float* g3   = (const float*)d_in[23];
    const float* be3  = (const float*)d_in[24];
    const float* m3   = (const float*)d_in[25];
    const float* v3   = (const float*)d_in[26];
    const float* Wl   = (const float*)d_in[27];
    const float* bl   = (const float*)d_in[28];
    const float* Wf   = (const float*)d_in[29];
    const float* bfp  = (const float*)d_in[30];

    char* ws = (char*)d_ws;
    size_t off = 0;
    auto alloc = [&](size_t bytes) -> void* {
        off = (off + 255) & ~(size_t)255;
        void* p = ws + off;
        off += bytes;
        return p;
    };

    float* bufA   = (float*)alloc((size_t)NN * 128 * 4);
    float* bufB   = (float*)alloc((size_t)NN * 128 * 4);
    int*   deg    = (int*)alloc((size_t)NN * 4);
    int*   offs   = (int*)alloc((size_t)(NN + 1) * 4);
    int*   cursor = (int*)alloc((size_t)NN * 4);
    int*   esrc   = (int*)alloc((size_t)NE * 4);
    int*   bsum   = (int*)alloc(256 * 4);
    int*   bcur   = (int*)alloc((size_t)NBUCK * 4);
    short* P1a    = (short*)alloc((size_t)2 * DIN * HID * 2);
    short* P1b    = (short*)alloc((size_t)2 * HID * HID * 2);
    short* P2a    = (short*)alloc((size_t)2 * HID * HID * 2);
    short* P3a    = (short*)alloc((size_t)2 * HID * HID * 2);
    short* P3b    = (short*)alloc((size_t)2 * HID * HID * 2);
    short* Pl     = (short*)alloc((size_t)2 * HID * HID * 2);
    // tmp (edge staging, int2 x NE = 12.8 MB) aliases bufB: only live during CSR
    // build, which completes before bufB's first GEMM write.
    int2*  tmp    = (int2*)bufB;

    const int NB_SCAN = (NN + 511) / 512;           // 196
    const int GRID_E  = (NE + 255) / 256;           // 6250
    const int GRID_G  = (NN + 127) / 128;           // 782 (GEMM, 128 rows/block)
    const int GRID_A64  = NN / 16;                  // 6250
    const int GRID_A128 = NN / 8;                   // 12500

    // ---- CSR build
    hipMemsetAsync(deg, 0, (size_t)NN * 4, stream);
    hist_kernel<<<GRID_E, 256, 0, stream>>>(eidx, deg);
    scan1_kernel<<<NB_SCAN, 512, 0, stream>>>(deg, offs, bsum);
    scan2_kernel<<<1, 256, 0, stream>>>(bsum, NB_SCAN);
    scan3_kernel<<<NB_SCAN, 512, 0, stream>>>(offs, bsum, cursor);
    initbcur_kernel<<<(NBUCK + 255) / 256, 256, 0, stream>>>(offs, bcur);
    bucket_kernel<<<GRID_E, 256, 0, stream>>>(eidx, bcur, tmp);
    place_kernel<<<NBUCK, 256, 0, stream>>>(offs, tmp, cursor, esrc);

    // ---- pack weights (bf16 hi/lo B-fragment order), one launch
    {
        dim3 grid(8, 6);
        packall_kernel<<<grid, 256, 0, stream>>>(W1a, W1b, W2a, W3a, W3b, Wl,
                                                 P1a, P1b, P2a, P3a, P3b, Pl);
    }

    // ---- layer 1
    agg_kernel<64><<<GRID_A64, 256, 0, stream>>>(x, offs, esrc, eps1, bufA);
    gemm_kernel<64, 0><<<GRID_G, 512, 0, stream>>>(bufA, P1a, b1a, nullptr, nullptr,
                                                   nullptr, nullptr, nullptr, nullptr,
                                                   bufB, NN);
    gemm_kernel<128, 1><<<GRID_G, 512, 0, stream>>>(bufB, P1b, b1b, g1, be1, m1, v1,
                                                    nullptr, nullptr, bufA, NN);
    // ---- layer 2
    agg_kernel<128><<<GRID_A128, 256, 0, stream>>>(bufA, offs, esrc, eps2, bufB);
    gemm_kernel<128, 1><<<GRID_G, 512, 0, stream>>>(bufB, P2a, b2a, g2, be2, m2, v2,
                                                    nullptr, nullptr, bufA, NN);
    // ---- layer 3
    agg_kernel<128><<<GRID_A128, 256, 0, stream>>>(bufA, offs, esrc, eps3, bufB);
    gemm_kernel<128, 0><<<GRID_G, 512, 0, stream>>>(bufB, P3a, b3a, nullptr, nullptr,
                                                    nullptr, nullptr, nullptr, nullptr,
                                                    bufA, NN);
    gemm_kernel<128, 1><<<GRID_G, 512, 0, stream>>>(bufA, P3b, b3b, g3, be3, m3, v3,
                                                    nullptr, nullptr, bufB, NN);
    // ---- head (Wl + Wf fused)
    gemm_kernel<128, 2><<<GRID_G, 512, 0, stream>>>(bufB, Pl, bl, nullptr, nullptr,
                                                    nullptr, nullptr, Wf, bfp,
                                                    (float*)d_out, NN);
}

// Round 4
// 639.531 us; speedup vs baseline: 1.3849x; 1.3849x over previous
//
#include <hip/hip_runtime.h>

// ---------------------------------------------------------------------------
// GIN forward on MI355X.
// CSR build (hist+scan+direct scatter) -> [agg (ILP gather) -> GEMM bf16x3] x3
// Layer-1 and layer-3 GEMM pairs fused through LDS (bf16 hi/lo planes).
// ---------------------------------------------------------------------------

constexpr int NN  = 100000;   // nodes
constexpr int NE  = 1600000;  // edges
constexpr int DIN = 64;
constexpr int HID = 128;

typedef __attribute__((ext_vector_type(4))) float f32x4;
typedef __attribute__((ext_vector_type(8))) short bf16x8;

__device__ __forceinline__ short f2bf(float f) {
    union { float f; unsigned u; } x; x.f = f;
    unsigned r = x.u + 0x7fffu + ((x.u >> 16) & 1u);   // RNE
    return (short)(r >> 16);
}
__device__ __forceinline__ float bf2f(short s) {
    union { unsigned u; float f; } x; x.u = ((unsigned)(unsigned short)s) << 16;
    return x.f;
}

// ---------------------------------------------------------------- CSR build
__global__ void hist_kernel(const int* __restrict__ eidx, int* __restrict__ deg) {
    int e = blockIdx.x * 256 + threadIdx.x;
    if (e < NE) atomicAdd(&deg[eidx[NE + e]], 1);
}

__global__ void scan1_kernel(const int* __restrict__ deg, int* __restrict__ offs,
                             int* __restrict__ bsum) {
    __shared__ int lds[512];
    int t = threadIdx.x;
    int i = blockIdx.x * 512 + t;
    int v = (i < NN) ? deg[i] : 0;
    lds[t] = v; __syncthreads();
    #pragma unroll
    for (int o = 1; o < 512; o <<= 1) {
        int x = (t >= o) ? lds[t - o] : 0;
        __syncthreads();
        lds[t] += x;
        __syncthreads();
    }
    if (i < NN) offs[i] = lds[t] - v;          // exclusive
    if (t == 511) bsum[blockIdx.x] = lds[511]; // block total
}

__global__ void scan2_kernel(int* __restrict__ bsum, int nb) {
    __shared__ int lds[256];
    int t = threadIdx.x;
    int v = (t < nb) ? bsum[t] : 0;
    lds[t] = v; __syncthreads();
    #pragma unroll
    for (int o = 1; o < 256; o <<= 1) {
        int x = (t >= o) ? lds[t - o] : 0;
        __syncthreads();
        lds[t] += x;
        __syncthreads();
    }
    if (t < nb) bsum[t] = lds[t] - v;          // exclusive block base
}

__global__ void scan3_kernel(int* __restrict__ offs, const int* __restrict__ bsum,
                             int* __restrict__ cursor) {
    int i = blockIdx.x * 512 + threadIdx.x;
    if (i < NN) {
        int val = offs[i] + bsum[blockIdx.x];
        offs[i] = val;
        cursor[i] = val;
    }
    if (i == 0) offs[NN] = NE;
}

// direct scatter: 100K cursors -> low atomic contention (127us measured r1)
__global__ void scatter_kernel(const int* __restrict__ eidx, int* __restrict__ cursor,
                               int* __restrict__ esrc) {
    int e = blockIdx.x * 256 + threadIdx.x;
    if (e < NE) {
        int d = eidx[NE + e];
        int p = atomicAdd(&cursor[d], 1);
        esrc[p] = eidx[e];
    }
}

// ---------------------------------------------------------------- aggregation
// out[n] = (1+eps)*h[n] + sum_{s in nbr(n)} h[s]   (D = 64 or 128, fp32)
// 8-deep unrolled gather for memory-level parallelism.
template<int D>
__global__ __launch_bounds__(256)
void agg_kernel(const float* __restrict__ h, const int* __restrict__ offs,
                const int* __restrict__ esrc, const float* __restrict__ epsp,
                float* __restrict__ out) {
    constexpr int TPN = D / 4;                 // threads per node (float4 lanes)
    int node = blockIdx.x * (256 / TPN) + threadIdx.x / TPN;
    int f4   = threadIdx.x % TPN;
    if (node >= NN) return;
    const f32x4* h4 = (const f32x4*)h;
    float eps = 1.0f + *epsp;
    int k  = offs[node];
    int k1 = offs[node + 1];
    f32x4 a0 = h4[(size_t)node * TPN + f4] * eps;
    f32x4 a1 = (f32x4)0.f, a2 = (f32x4)0.f, a3 = (f32x4)0.f;
    for (; k + 8 <= k1; k += 8) {
        int s0 = esrc[k+0], s1 = esrc[k+1], s2 = esrc[k+2], s3 = esrc[k+3];
        int s4 = esrc[k+4], s5 = esrc[k+5], s6 = esrc[k+6], s7 = esrc[k+7];
        f32x4 t0 = h4[(size_t)s0*TPN+f4], t1 = h4[(size_t)s1*TPN+f4];
        f32x4 t2 = h4[(size_t)s2*TPN+f4], t3 = h4[(size_t)s3*TPN+f4];
        f32x4 t4 = h4[(size_t)s4*TPN+f4], t5 = h4[(size_t)s5*TPN+f4];
        f32x4 t6 = h4[(size_t)s6*TPN+f4], t7 = h4[(size_t)s7*TPN+f4];
        a0 += t0; a1 += t1; a2 += t2; a3 += t3;
        a0 += t4; a1 += t5; a2 += t6; a3 += t7;
    }
    for (; k + 2 <= k1; k += 2) {
        f32x4 t0 = h4[(size_t)esrc[k]*TPN+f4];
        f32x4 t1 = h4[(size_t)esrc[k+1]*TPN+f4];
        a0 += t0; a1 += t1;
    }
    if (k < k1) a2 += h4[(size_t)esrc[k]*TPN+f4];
    ((f32x4*)out)[(size_t)node * TPN + f4] = (a0 + a1) + (a2 + a3);
}

// ---------------------------------------------------------------- weight pack
// All 6 weight matrices in one launch. Pack W[K][128] (fp32) into B-fragment
// order for mfma_f32_16x16x32_bf16, split hi/lo halves.
// frag: P[c][nt][lane][j] = bf16( W[c*32 + (lane>>4)*8 + j][nt*16 + (lane&15)] )
__global__ void packall_kernel(const float* __restrict__ W1a, const float* __restrict__ W1b,
                               const float* __restrict__ W2a, const float* __restrict__ W3a,
                               const float* __restrict__ W3b, const float* __restrict__ Wl,
                               short* P1a, short* P1b, short* P2a,
                               short* P3a, short* P3b, short* Pl) {
    const float* W; short* P; int K;
    switch (blockIdx.y) {
        case 0: W = W1a; P = P1a; K = 64;  break;
        case 1: W = W1b; P = P1b; K = 128; break;
        case 2: W = W2a; P = P2a; K = 128; break;
        case 3: W = W3a; P = P3a; K = 128; break;
        case 4: W = W3b; P = P3b; K = 128; break;
        default: W = Wl; P = Pl;  K = 128; break;
    }
    int T = (K / 32) * 8 * 64;
    int idx = blockIdx.x * 256 + threadIdx.x;
    if (idx >= T) return;
    int c  = idx >> 9;
    int nt = (idx >> 6) & 7;
    int l  = idx & 63;
    int col   = nt * 16 + (l & 15);
    int kbase = c * 32 + (l >> 4) * 8;
    bf16x8 hi, lo;
    #pragma unroll
    for (int j = 0; j < 8; ++j) {
        float w = W[(kbase + j) * HID + col];
        short h = f2bf(w);
        hi[j] = h;
        lo[j] = f2bf(w - bf2f(h));
    }
    *(bf16x8*)&P[(size_t)idx * 8]       = hi;
    *(bf16x8*)&P[(size_t)(T + idx) * 8] = lo;
}

// ---------------------------------------------------------------- single GEMM
// C[M,128] = epilogue(A[M,K] @ W[K,128])   via bf16x3 split products.
// 512 threads, 128 rows/block, W staged in LDS.
// MODE 1: bn(relu(.+bias))      -> out[M,128]
// MODE 2: head: dot(relu(.+bias), Wf) + bf -> out[M]
template<int K, int MODE>
__global__ __launch_bounds__(512)
void gemm_kernel(const float* __restrict__ A, const short* __restrict__ P,
                 const float* __restrict__ bias,
                 const float* __restrict__ g, const float* __restrict__ be,
                 const float* __restrict__ m, const float* __restrict__ v,
                 const float* __restrict__ Wf, const float* __restrict__ bf,
                 float* __restrict__ out, int M) {
    constexpr int NCH = K / 32;
    constexpr int T   = NCH * 8 * 64;          // frags per half (hi or lo)
    __shared__ short wlds[2 * T * 8];

    const int tid  = threadIdx.x;
    const int wid  = tid >> 6;
    const int lane = tid & 63;

    for (int i = tid; i < 2 * T; i += 512)
        ((bf16x8*)wlds)[i] = ((const bf16x8*)P)[i];
    __syncthreads();

    const int rlo  = lane & 15;
    const int kgrp = lane >> 4;
    const int row  = blockIdx.x * 128 + wid * 16 + rlo;
    const int r    = row < M ? row : M - 1;
    const float* arow = A + (size_t)r * K + kgrp * 8;

    f32x4 acc[8];
    #pragma unroll
    for (int i = 0; i < 8; ++i) acc[i] = (f32x4)0.0f;

    #pragma unroll
    for (int c = 0; c < NCH; ++c) {
        f32x4 a0 = *(const f32x4*)(arow + c * 32);
        f32x4 a1 = *(const f32x4*)(arow + c * 32 + 4);
        bf16x8 ah, al;
        #pragma unroll
        for (int j = 0; j < 4; ++j) {
            short h0 = f2bf(a0[j]);
            short h1 = f2bf(a1[j]);
            ah[j]     = h0;
            ah[j + 4] = h1;
            al[j]     = f2bf(a0[j] - bf2f(h0));
            al[j + 4] = f2bf(a1[j] - bf2f(h1));
        }
        #pragma unroll
        for (int nt = 0; nt < 8; ++nt) {
            int fi = ((c * 8) + nt) * 64 + lane;
            bf16x8 wh = *(bf16x8*)&wlds[(size_t)fi * 8];
            bf16x8 wl = *(bf16x8*)&wlds[(size_t)(T + fi) * 8];
            acc[nt] = __builtin_amdgcn_mfma_f32_16x16x32_bf16(ah, wh, acc[nt], 0, 0, 0);
            acc[nt] = __builtin_amdgcn_mfma_f32_16x16x32_bf16(al, wh, acc[nt], 0, 0, 0);
            acc[nt] = __builtin_amdgcn_mfma_f32_16x16x32_bf16(ah, wl, acc[nt], 0, 0, 0);
        }
    }

    if constexpr (MODE == 2) {
        float p0 = 0, p1 = 0, p2 = 0, p3 = 0;
        #pragma unroll
        for (int nt = 0; nt < 8; ++nt) {
            int col  = nt * 16 + (lane & 15);
            float bb = bias[col];
            float wv = Wf[col];
            p0 += fmaxf(acc[nt][0] + bb, 0.f) * wv;
            p1 += fmaxf(acc[nt][1] + bb, 0.f) * wv;
            p2 += fmaxf(acc[nt][2] + bb, 0.f) * wv;
            p3 += fmaxf(acc[nt][3] + bb, 0.f) * wv;
        }
        #pragma unroll
        for (int o = 1; o < 16; o <<= 1) {
            p0 += __shfl_xor(p0, o);
            p1 += __shfl_xor(p1, o);
            p2 += __shfl_xor(p2, o);
            p3 += __shfl_xor(p3, o);
        }
        if ((lane & 15) == 0) {
            int rbase = blockIdx.x * 128 + wid * 16 + kgrp * 4;
            float bfv = bf[0];
            if (rbase + 0 < M) out[rbase + 0] = p0 + bfv;
            if (rbase + 1 < M) out[rbase + 1] = p1 + bfv;
            if (rbase + 2 < M) out[rbase + 2] = p2 + bfv;
            if (rbase + 3 < M) out[rbase + 3] = p3 + bfv;
        }
    } else {
        #pragma unroll
        for (int nt = 0; nt < 8; ++nt) {
            int col  = nt * 16 + (lane & 15);
            float bb = bias[col];
            float sv = g[col] * rsqrtf(v[col] + 1e-5f);
            float tv = be[col] - m[col] * sv;
            #pragma unroll
            for (int jj = 0; jj < 4; ++jj) {
                int rr = blockIdx.x * 128 + wid * 16 + kgrp * 4 + jj;
                float val = fmaxf(acc[nt][jj] + bb, 0.f) * sv + tv;
                if (rr < M) out[(size_t)rr * 128 + col] = val;
            }
        }
    }
}

// ---------------------------------------------------------------- fused pair
// out = bn(relu( relu(A@W1 + b1) @ W2 + b2 ))
// 256 threads, 64 rows/block. W frags read from global (L2-resident).
// Intermediate h1 kept in LDS as bf16 hi/lo planes (wave-local 16-row bands),
// read back directly as MFMA A-fragments.
template<int K1>
__global__ __launch_bounds__(256)
void fused2_kernel(const float* __restrict__ A,
                   const short* __restrict__ P1, const float* __restrict__ bias1,
                   const short* __restrict__ P2, const float* __restrict__ bias2,
                   const float* __restrict__ g, const float* __restrict__ be,
                   const float* __restrict__ m, const float* __restrict__ v,
                   float* __restrict__ out, int M) {
    constexpr int NCH1 = K1 / 32;
    constexpr int T1   = NCH1 * 8 * 64;
    constexpr int T2   = 4 * 8 * 64;
    constexpr int LDW  = 136;                 // shorts per row (16B aligned, padded)
    __shared__ short h1hi[64 * LDW];
    __shared__ short h1lo[64 * LDW];

    const int tid  = threadIdx.x;
    const int wid  = tid >> 6;
    const int lane = tid & 63;
    const int rlo  = lane & 15;
    const int kgrp = lane >> 4;

    const int row = blockIdx.x * 64 + wid * 16 + rlo;
    const int r   = row < M ? row : M - 1;
    const float* arow = A + (size_t)r * K1 + kgrp * 8;

    const bf16x8* P1v = (const bf16x8*)P1;
    const bf16x8* P2v = (const bf16x8*)P2;

    f32x4 acc[8];
    #pragma unroll
    for (int i = 0; i < 8; ++i) acc[i] = (f32x4)0.0f;

    // ---- GEMM1: A (global fp32) x W1 (global frags)
    #pragma unroll
    for (int c = 0; c < NCH1; ++c) {
        f32x4 a0 = *(const f32x4*)(arow + c * 32);
        f32x4 a1 = *(const f32x4*)(arow + c * 32 + 4);
        bf16x8 ah, al;
        #pragma unroll
        for (int j = 0; j < 4; ++j) {
            short h0 = f2bf(a0[j]);
            short h1 = f2bf(a1[j]);
            ah[j]     = h0;
            ah[j + 4] = h1;
            al[j]     = f2bf(a0[j] - bf2f(h0));
            al[j + 4] = f2bf(a1[j] - bf2f(h1));
        }
        #pragma unroll
        for (int nt = 0; nt < 8; ++nt) {
            int fi = ((c * 8) + nt) * 64 + lane;
            bf16x8 wh = P1v[fi];
            bf16x8 wl = P1v[T1 + fi];
            acc[nt] = __builtin_amdgcn_mfma_f32_16x16x32_bf16(ah, wh, acc[nt], 0, 0, 0);
            acc[nt] = __builtin_amdgcn_mfma_f32_16x16x32_bf16(al, wh, acc[nt], 0, 0, 0);
            acc[nt] = __builtin_amdgcn_mfma_f32_16x16x32_bf16(ah, wl, acc[nt], 0, 0, 0);
        }
    }

    // ---- epilogue1: relu(+bias1), split to bf16 hi/lo in LDS
    #pragma unroll
    for (int nt = 0; nt < 8; ++nt) {
        int col  = nt * 16 + rlo;
        float bb = bias1[col];
        #pragma unroll
        for (int jj = 0; jj < 4; ++jj) {
            int lr = wid * 16 + kgrp * 4 + jj;
            float val = fmaxf(acc[nt][jj] + bb, 0.f);
            short h = f2bf(val);
            h1hi[lr * LDW + col] = h;
            h1lo[lr * LDW + col] = f2bf(val - bf2f(h));
        }
    }
    __syncthreads();

    // ---- GEMM2: h1 (LDS bf16 hi/lo) x W2 (global frags)
    f32x4 acc2[8];
    #pragma unroll
    for (int i = 0; i < 8; ++i) acc2[i] = (f32x4)0.0f;
    const int lr2 = wid * 16 + rlo;
    #pragma unroll
    for (int c = 0; c < 4; ++c) {
        bf16x8 ah = *(bf16x8*)&h1hi[lr2 * LDW + c * 32 + kgrp * 8];
        bf16x8 al = *(bf16x8*)&h1lo[lr2 * LDW + c * 32 + kgrp * 8];
        #pragma unroll
        for (int nt = 0; nt < 8; ++nt) {
            int fi = ((c * 8) + nt) * 64 + lane;
            bf16x8 wh = P2v[fi];
            bf16x8 wl = P2v[T2 + fi];
            acc2[nt] = __builtin_amdgcn_mfma_f32_16x16x32_bf16(ah, wh, acc2[nt], 0, 0, 0);
            acc2[nt] = __builtin_amdgcn_mfma_f32_16x16x32_bf16(al, wh, acc2[nt], 0, 0, 0);
            acc2[nt] = __builtin_amdgcn_mfma_f32_16x16x32_bf16(ah, wl, acc2[nt], 0, 0, 0);
        }
    }

    // ---- epilogue2: bn(relu(+bias2)) -> global
    #pragma unroll
    for (int nt = 0; nt < 8; ++nt) {
        int col  = nt * 16 + rlo;
        float bb = bias2[col];
        float sv = g[col] * rsqrtf(v[col] + 1e-5f);
        float tv = be[col] - m[col] * sv;
        #pragma unroll
        for (int jj = 0; jj < 4; ++jj) {
            int rr = blockIdx.x * 64 + wid * 16 + kgrp * 4 + jj;
            float val = fmaxf(acc2[nt][jj] + bb, 0.f) * sv + tv;
            if (rr < M) out[(size_t)rr * 128 + col] = val;
        }
    }
}

// ---------------------------------------------------------------------------
extern "C" void kernel_launch(void* const* d_in, const int* in_sizes, int n_in,
                              void* d_out, int out_size, void* d_ws, size_t ws_size,
                              hipStream_t stream) {
    const float* x    = (const float*)d_in[0];
    const int*   eidx = (const int*)d_in[1];
    const float* eps1 = (const float*)d_in[2];
    const float* W1a  = (const float*)d_in[3];
    const float* b1a  = (const float*)d_in[4];
    const float* W1b  = (const float*)d_in[5];
    const float* b1b  = (const float*)d_in[6];
    const float* g1   = (const float*)d_in[7];
    const float* be1  = (const float*)d_in[8];
    const float* m1   = (const float*)d_in[9];
    const float* v1   = (const float*)d_in[10];
    const float* eps2 = (const float*)d_in[11];
    const float* W2a  = (const float*)d_in[12];
    const float* b2a  = (const float*)d_in[13];
    const float* g2   = (const float*)d_in[14];
    const float* be2  = (const float*)d_in[15];
    const float* m2   = (const float*)d_in[16];
    const float* v2   = (const float*)d_in[17];
    const float* eps3 = (const float*)d_in[18];
    const float* W3a  = (const float*)d_in[19];
    const float* b3a  = (const float*)d_in[20];
    const float* W3b  = (const float*)d_in[21];
    const float* b3b  = (const float*)d_in[22];
    const float* g3   = (const float*)d_in[23];
    const float* be3  = (const float*)d_in[24];
    const float* m3   = (const float*)d_in[25];
    const float* v3   = (const float*)d_in[26];
    const float* Wl   = (const float*)d_in[27];
    const float* bl   = (const float*)d_in[28];
    const float* Wf   = (const float*)d_in[29];
    const float* bfp  = (const float*)d_in[30];

    char* ws = (char*)d_ws;
    size_t off = 0;
    auto alloc = [&](size_t bytes) -> void* {
        off = (off + 255) & ~(size_t)255;
        void* p = ws + off;
        off += bytes;
        return p;
    };

    float* bufA   = (float*)alloc((size_t)NN * 128 * 4);
    float* bufB   = (float*)alloc((size_t)NN * 128 * 4);
    int*   deg    = (int*)alloc((size_t)NN * 4);
    int*   offs   = (int*)alloc((size_t)(NN + 1) * 4);
    int*   cursor = (int*)alloc((size_t)NN * 4);
    int*   esrc   = (int*)alloc((size_t)NE * 4);
    int*   bsum   = (int*)alloc(256 * 4);
    short* P1a    = (short*)alloc((size_t)2 * DIN * HID * 2);
    short* P1b    = (short*)alloc((size_t)2 * HID * HID * 2);
    short* P2a    = (short*)alloc((size_t)2 * HID * HID * 2);
    short* P3a    = (short*)alloc((size_t)2 * HID * HID * 2);
    short* P3b    = (short*)alloc((size_t)2 * HID * HID * 2);
    short* Pl     = (short*)alloc((size_t)2 * HID * HID * 2);

    const int NB_SCAN = (NN + 511) / 512;           // 196
    const int GRID_E  = (NE + 255) / 256;           // 6250
    const int GRID_G  = (NN + 127) / 128;           // 782  (single GEMM, 128 rows)
    const int GRID_F  = (NN + 63) / 64;             // 1563 (fused GEMM, 64 rows)
    const int GRID_A64  = NN / 16;                  // 6250
    const int GRID_A128 = NN / 8;                   // 12500

    // ---- CSR build
    hipMemsetAsync(deg, 0, (size_t)NN * 4, stream);
    hist_kernel<<<GRID_E, 256, 0, stream>>>(eidx, deg);
    scan1_kernel<<<NB_SCAN, 512, 0, stream>>>(deg, offs, bsum);
    scan2_kernel<<<1, 256, 0, stream>>>(bsum, NB_SCAN);
    scan3_kernel<<<NB_SCAN, 512, 0, stream>>>(offs, bsum, cursor);
    scatter_kernel<<<GRID_E, 256, 0, stream>>>(eidx, cursor, esrc);

    // ---- pack weights (bf16 hi/lo B-fragment order), one launch
    {
        dim3 grid(8, 6);
        packall_kernel<<<grid, 256, 0, stream>>>(W1a, W1b, W2a, W3a, W3b, Wl,
                                                 P1a, P1b, P2a, P3a, P3b, Pl);
    }

    // ---- layer 1 (agg -> fused W1a+W1b+BN)
    agg_kernel<64><<<GRID_A64, 256, 0, stream>>>(x, offs, esrc, eps1, bufA);
    fused2_kernel<64><<<GRID_F, 256, 0, stream>>>(bufA, P1a, b1a, P1b, b1b,
                                                  g1, be1, m1, v1, bufB, NN);
    // ---- layer 2 (agg -> single GEMM+BN)
    agg_kernel<128><<<GRID_A128, 256, 0, stream>>>(bufB, offs, esrc, eps2, bufA);
    gemm_kernel<128, 1><<<GRID_G, 512, 0, stream>>>(bufA, P2a, b2a, g2, be2, m2, v2,
                                                    nullptr, nullptr, bufB, NN);
    // ---- layer 3 (agg -> fused W3a+W3b+BN)
    agg_kernel<128><<<GRID_A128, 256, 0, stream>>>(bufB, offs, esrc, eps3, bufA);
    fused2_kernel<128><<<GRID_F, 256, 0, stream>>>(bufA, P3a, b3a, P3b, b3b,
                                                   g3, be3, m3, v3, bufB, NN);
    // ---- head (Wl + Wf fused in-register)
    gemm_kernel<128, 2><<<GRID_G, 512, 0, stream>>>(bufB, Pl, bl, nullptr, nullptr,
                                                    nullptr, nullptr, Wf, bfp,
                                                    (float*)d_out, NN);
}

// Round 5
// 531.109 us; speedup vs baseline: 1.6676x; 1.2041x over previous
//
#include <hip/hip_runtime.h>

// ---------------------------------------------------------------------------
// GIN forward on MI355X.
// CSR build (hist+scan+direct scatter) -> [agg (bf16 gather) -> GEMM bf16x3] x3
// Layer-1 pair fused; layer-3 pair + head fused (3 GEMM stages, one kernel).
// Aggregation gathers a bf16 copy of h (half the random-read bytes); self term
// and accumulation stay fp32.
// ---------------------------------------------------------------------------

constexpr int NN  = 100000;   // nodes
constexpr int NE  = 1600000;  // edges
constexpr int DIN = 64;
constexpr int HID = 128;

typedef __attribute__((ext_vector_type(4))) float f32x4;
typedef __attribute__((ext_vector_type(8))) short bf16x8;
typedef __attribute__((ext_vector_type(8))) unsigned short u16x8;

__device__ __forceinline__ short f2bf(float f) {
    union { float f; unsigned u; } x; x.f = f;
    unsigned r = x.u + 0x7fffu + ((x.u >> 16) & 1u);   // RNE
    return (short)(r >> 16);
}
__device__ __forceinline__ float bf2f(short s) {
    union { unsigned u; float f; } x; x.u = ((unsigned)(unsigned short)s) << 16;
    return x.f;
}

// ---------------------------------------------------------------- CSR build
__global__ void hist_kernel(const int* __restrict__ eidx, int* __restrict__ deg) {
    int e = blockIdx.x * 256 + threadIdx.x;
    if (e < NE) atomicAdd(&deg[eidx[NE + e]], 1);
}

__global__ void scan1_kernel(const int* __restrict__ deg, int* __restrict__ offs,
                             int* __restrict__ bsum) {
    __shared__ int lds[512];
    int t = threadIdx.x;
    int i = blockIdx.x * 512 + t;
    int v = (i < NN) ? deg[i] : 0;
    lds[t] = v; __syncthreads();
    #pragma unroll
    for (int o = 1; o < 512; o <<= 1) {
        int x = (t >= o) ? lds[t - o] : 0;
        __syncthreads();
        lds[t] += x;
        __syncthreads();
    }
    if (i < NN) offs[i] = lds[t] - v;          // exclusive
    if (t == 511) bsum[blockIdx.x] = lds[511]; // block total
}

__global__ void scan2_kernel(int* __restrict__ bsum, int nb) {
    __shared__ int lds[256];
    int t = threadIdx.x;
    int v = (t < nb) ? bsum[t] : 0;
    lds[t] = v; __syncthreads();
    #pragma unroll
    for (int o = 1; o < 256; o <<= 1) {
        int x = (t >= o) ? lds[t - o] : 0;
        __syncthreads();
        lds[t] += x;
        __syncthreads();
    }
    if (t < nb) bsum[t] = lds[t] - v;          // exclusive block base
}

__global__ void scan3_kernel(int* __restrict__ offs, const int* __restrict__ bsum,
                             int* __restrict__ cursor) {
    int i = blockIdx.x * 512 + threadIdx.x;
    if (i < NN) {
        int val = offs[i] + bsum[blockIdx.x];
        offs[i] = val;
        cursor[i] = val;
    }
    if (i == 0) offs[NN] = NE;
}

// direct scatter: 100K cursors -> low atomic contention (127us measured r1)
__global__ void scatter_kernel(const int* __restrict__ eidx, int* __restrict__ cursor,
                               int* __restrict__ esrc) {
    int e = blockIdx.x * 256 + threadIdx.x;
    if (e < NE) {
        int d = eidx[NE + e];
        int p = atomicAdd(&cursor[d], 1);
        esrc[p] = eidx[e];
    }
}

// ---------------------------------------------------------------- x -> bf16
__global__ void cvt_kernel(const float* __restrict__ x, unsigned short* __restrict__ xb) {
    int i = blockIdx.x * 256 + threadIdx.x;       // ushort8 index
    if (i >= NN * DIN / 8) return;
    const f32x4* p = (const f32x4*)x + (size_t)i * 2;
    f32x4 v0 = p[0], v1 = p[1];
    u16x8 o;
    #pragma unroll
    for (int j = 0; j < 4; ++j) {
        o[j]     = (unsigned short)f2bf(v0[j]);
        o[j + 4] = (unsigned short)f2bf(v1[j]);
    }
    ((u16x8*)xb)[i] = o;
}

// ---------------------------------------------------------------- aggregation
// out[n] = (1+eps)*hf[n] + sum_{s in nbr(n)} hb[s]
// hf: fp32 (self term, full precision); hb: bf16 copy (gathered, half bytes).
template<int D>
__global__ __launch_bounds__(256)
void aggb_kernel(const float* __restrict__ hf, const unsigned short* __restrict__ hb,
                 const int* __restrict__ offs, const int* __restrict__ esrc,
                 const float* __restrict__ epsp, float* __restrict__ out) {
    constexpr int TPN = D / 8;                 // lanes per node (ushort8 each)
    int node = blockIdx.x * (256 / TPN) + threadIdx.x / TPN;
    int f    = threadIdx.x % TPN;
    if (node >= NN) return;
    const u16x8* h8 = (const u16x8*)hb;
    float eps = 1.0f + *epsp;

    const float* hrow = hf + (size_t)node * D + f * 8;
    f32x4 a0 = *(const f32x4*)hrow * eps;
    f32x4 a1 = *(const f32x4*)(hrow + 4) * eps;
    f32x4 b0 = (f32x4)0.f, b1 = (f32x4)0.f;

    union { unsigned u; float fv; } cvt;
    auto acc8 = [&](u16x8 t, f32x4& x0, f32x4& x1) {
        #pragma unroll
        for (int j = 0; j < 4; ++j) { cvt.u = ((unsigned)t[j]) << 16;     x0[j] += cvt.fv; }
        #pragma unroll
        for (int j = 0; j < 4; ++j) { cvt.u = ((unsigned)t[j + 4]) << 16; x1[j] += cvt.fv; }
    };

    int k = offs[node], k1 = offs[node + 1];
    for (; k + 8 <= k1; k += 8) {
        int s0 = esrc[k+0], s1 = esrc[k+1], s2 = esrc[k+2], s3 = esrc[k+3];
        int s4 = esrc[k+4], s5 = esrc[k+5], s6 = esrc[k+6], s7 = esrc[k+7];
        u16x8 t0 = h8[(size_t)s0*TPN+f], t1 = h8[(size_t)s1*TPN+f];
        u16x8 t2 = h8[(size_t)s2*TPN+f], t3 = h8[(size_t)s3*TPN+f];
        u16x8 t4 = h8[(size_t)s4*TPN+f], t5 = h8[(size_t)s5*TPN+f];
        u16x8 t6 = h8[(size_t)s6*TPN+f], t7 = h8[(size_t)s7*TPN+f];
        acc8(t0, a0, a1); acc8(t1, b0, b1); acc8(t2, a0, a1); acc8(t3, b0, b1);
        acc8(t4, a0, a1); acc8(t5, b0, b1); acc8(t6, a0, a1); acc8(t7, b0, b1);
    }
    for (; k + 2 <= k1; k += 2) {
        u16x8 t0 = h8[(size_t)esrc[k]*TPN+f];
        u16x8 t1 = h8[(size_t)esrc[k+1]*TPN+f];
        acc8(t0, a0, a1); acc8(t1, b0, b1);
    }
    if (k < k1) acc8(h8[(size_t)esrc[k]*TPN+f], a0, a1);

    float* orow = out + (size_t)node * D + f * 8;
    *(f32x4*)orow       = a0 + b0;
    *(f32x4*)(orow + 4) = a1 + b1;
}

// ---------------------------------------------------------------- weight pack
// frag: P[c][nt][lane][j] = bf16( W[c*32 + (lane>>4)*8 + j][nt*16 + (lane&15)] )
__global__ void packall_kernel(const float* __restrict__ W1a, const float* __restrict__ W1b,
                               const float* __restrict__ W2a, const float* __restrict__ W3a,
                               const float* __restrict__ W3b, const float* __restrict__ Wl,
                               short* P1a, short* P1b, short* P2a,
                               short* P3a, short* P3b, short* Pl) {
    const float* W; short* P; int K;
    switch (blockIdx.y) {
        case 0: W = W1a; P = P1a; K = 64;  break;
        case 1: W = W1b; P = P1b; K = 128; break;
        case 2: W = W2a; P = P2a; K = 128; break;
        case 3: W = W3a; P = P3a; K = 128; break;
        case 4: W = W3b; P = P3b; K = 128; break;
        default: W = Wl; P = Pl;  K = 128; break;
    }
    int T = (K / 32) * 8 * 64;
    int idx = blockIdx.x * 256 + threadIdx.x;
    if (idx >= T) return;
    int c  = idx >> 9;
    int nt = (idx >> 6) & 7;
    int l  = idx & 63;
    int col   = nt * 16 + (l & 15);
    int kbase = c * 32 + (l >> 4) * 8;
    bf16x8 hi, lo;
    #pragma unroll
    for (int j = 0; j < 8; ++j) {
        float w = W[(kbase + j) * HID + col];
        short h = f2bf(w);
        hi[j] = h;
        lo[j] = f2bf(w - bf2f(h));
    }
    *(bf16x8*)&P[(size_t)idx * 8]       = hi;
    *(bf16x8*)&P[(size_t)(T + idx) * 8] = lo;
}

// ---------------------------------------------------------------- single GEMM
// out = bn(relu(A@W + bias)); also writes bf16 copy hbout. 512 thr, 128 rows.
__global__ __launch_bounds__(512)
void gemm_bn_kernel(const float* __restrict__ A, const short* __restrict__ P,
                    const float* __restrict__ bias,
                    const float* __restrict__ g, const float* __restrict__ be,
                    const float* __restrict__ m, const float* __restrict__ v,
                    float* __restrict__ out, unsigned short* __restrict__ hbout, int M) {
    constexpr int NCH = 4;
    constexpr int T   = NCH * 8 * 64;
    __shared__ short wlds[2 * T * 8];

    const int tid  = threadIdx.x;
    const int wid  = tid >> 6;
    const int lane = tid & 63;

    for (int i = tid; i < 2 * T; i += 512)
        ((bf16x8*)wlds)[i] = ((const bf16x8*)P)[i];
    __syncthreads();

    const int rlo  = lane & 15;
    const int kgrp = lane >> 4;
    const int row  = blockIdx.x * 128 + wid * 16 + rlo;
    const int r    = row < M ? row : M - 1;
    const float* arow = A + (size_t)r * 128 + kgrp * 8;

    f32x4 acc[8];
    #pragma unroll
    for (int i = 0; i < 8; ++i) acc[i] = (f32x4)0.0f;

    #pragma unroll
    for (int c = 0; c < NCH; ++c) {
        f32x4 a0 = *(const f32x4*)(arow + c * 32);
        f32x4 a1 = *(const f32x4*)(arow + c * 32 + 4);
        bf16x8 ah, al;
        #pragma unroll
        for (int j = 0; j < 4; ++j) {
            short h0 = f2bf(a0[j]);
            short h1 = f2bf(a1[j]);
            ah[j]     = h0;
            ah[j + 4] = h1;
            al[j]     = f2bf(a0[j] - bf2f(h0));
            al[j + 4] = f2bf(a1[j] - bf2f(h1));
        }
        #pragma unroll
        for (int nt = 0; nt < 8; ++nt) {
            int fi = ((c * 8) + nt) * 64 + lane;
            bf16x8 wh = *(bf16x8*)&wlds[(size_t)fi * 8];
            bf16x8 wl = *(bf16x8*)&wlds[(size_t)(T + fi) * 8];
            acc[nt] = __builtin_amdgcn_mfma_f32_16x16x32_bf16(ah, wh, acc[nt], 0, 0, 0);
            acc[nt] = __builtin_amdgcn_mfma_f32_16x16x32_bf16(al, wh, acc[nt], 0, 0, 0);
            acc[nt] = __builtin_amdgcn_mfma_f32_16x16x32_bf16(ah, wl, acc[nt], 0, 0, 0);
        }
    }

    #pragma unroll
    for (int nt = 0; nt < 8; ++nt) {
        int col  = nt * 16 + rlo;
        float bb = bias[col];
        float sv = g[col] * rsqrtf(v[col] + 1e-5f);
        float tv = be[col] - m[col] * sv;
        #pragma unroll
        for (int jj = 0; jj < 4; ++jj) {
            int rr = blockIdx.x * 128 + wid * 16 + kgrp * 4 + jj;
            float val = fmaxf(acc[nt][jj] + bb, 0.f) * sv + tv;
            if (rr < M) {
                out[(size_t)rr * 128 + col] = val;
                hbout[(size_t)rr * 128 + col] = (unsigned short)f2bf(val);
            }
        }
    }
}

// ---------------------------------------------------------------- fused pair
// out = bn(relu( relu(A@W1 + b1) @ W2 + b2 ));  bf16 copy to hbout.
// 256 threads, 64 rows/block. W frags from global (L2-resident).
template<int K1>
__global__ __launch_bounds__(256)
void fused2_kernel(const float* __restrict__ A,
                   const short* __restrict__ P1, const float* __restrict__ bias1,
                   const short* __restrict__ P2, const float* __restrict__ bias2,
                   const float* __restrict__ g, const float* __restrict__ be,
                   const float* __restrict__ m, const float* __restrict__ v,
                   float* __restrict__ out, unsigned short* __restrict__ hbout, int M) {
    constexpr int NCH1 = K1 / 32;
    constexpr int T1   = NCH1 * 8 * 64;
    constexpr int T2   = 4 * 8 * 64;
    constexpr int LDW  = 136;
    __shared__ short h1hi[64 * LDW];
    __shared__ short h1lo[64 * LDW];

    const int tid  = threadIdx.x;
    const int wid  = tid >> 6;
    const int lane = tid & 63;
    const int rlo  = lane & 15;
    const int kgrp = lane >> 4;

    const int row = blockIdx.x * 64 + wid * 16 + rlo;
    const int r   = row < M ? row : M - 1;
    const float* arow = A + (size_t)r * K1 + kgrp * 8;

    const bf16x8* P1v = (const bf16x8*)P1;
    const bf16x8* P2v = (const bf16x8*)P2;

    f32x4 acc[8];
    #pragma unroll
    for (int i = 0; i < 8; ++i) acc[i] = (f32x4)0.0f;

    #pragma unroll
    for (int c = 0; c < NCH1; ++c) {
        f32x4 a0 = *(const f32x4*)(arow + c * 32);
        f32x4 a1 = *(const f32x4*)(arow + c * 32 + 4);
        bf16x8 ah, al;
        #pragma unroll
        for (int j = 0; j < 4; ++j) {
            short h0 = f2bf(a0[j]);
            short h1 = f2bf(a1[j]);
            ah[j]     = h0;
            ah[j + 4] = h1;
            al[j]     = f2bf(a0[j] - bf2f(h0));
            al[j + 4] = f2bf(a1[j] - bf2f(h1));
        }
        #pragma unroll
        for (int nt = 0; nt < 8; ++nt) {
            int fi = ((c * 8) + nt) * 64 + lane;
            bf16x8 wh = P1v[fi];
            bf16x8 wl = P1v[T1 + fi];
            acc[nt] = __builtin_amdgcn_mfma_f32_16x16x32_bf16(ah, wh, acc[nt], 0, 0, 0);
            acc[nt] = __builtin_amdgcn_mfma_f32_16x16x32_bf16(al, wh, acc[nt], 0, 0, 0);
            acc[nt] = __builtin_amdgcn_mfma_f32_16x16x32_bf16(ah, wl, acc[nt], 0, 0, 0);
        }
    }

    #pragma unroll
    for (int nt = 0; nt < 8; ++nt) {
        int col  = nt * 16 + rlo;
        float bb = bias1[col];
        #pragma unroll
        for (int jj = 0; jj < 4; ++jj) {
            int lr = wid * 16 + kgrp * 4 + jj;
            float val = fmaxf(acc[nt][jj] + bb, 0.f);
            short h = f2bf(val);
            h1hi[lr * LDW + col] = h;
            h1lo[lr * LDW + col] = f2bf(val - bf2f(h));
        }
    }
    __syncthreads();

    f32x4 acc2[8];
    #pragma unroll
    for (int i = 0; i < 8; ++i) acc2[i] = (f32x4)0.0f;
    const int lr2 = wid * 16 + rlo;
    #pragma unroll
    for (int c = 0; c < 4; ++c) {
        bf16x8 ah = *(bf16x8*)&h1hi[lr2 * LDW + c * 32 + kgrp * 8];
        bf16x8 al = *(bf16x8*)&h1lo[lr2 * LDW + c * 32 + kgrp * 8];
        #pragma unroll
        for (int nt = 0; nt < 8; ++nt) {
            int fi = ((c * 8) + nt) * 64 + lane;
            bf16x8 wh = P2v[fi];
            bf16x8 wl = P2v[T2 + fi];
            acc2[nt] = __builtin_amdgcn_mfma_f32_16x16x32_bf16(ah, wh, acc2[nt], 0, 0, 0);
            acc2[nt] = __builtin_amdgcn_mfma_f32_16x16x32_bf16(al, wh, acc2[nt], 0, 0, 0);
            acc2[nt] = __builtin_amdgcn_mfma_f32_16x16x32_bf16(ah, wl, acc2[nt], 0, 0, 0);
        }
    }

    #pragma unroll
    for (int nt = 0; nt < 8; ++nt) {
        int col  = nt * 16 + rlo;
        float bb = bias2[col];
        float sv = g[col] * rsqrtf(v[col] + 1e-5f);
        float tv = be[col] - m[col] * sv;
        #pragma unroll
        for (int jj = 0; jj < 4; ++jj) {
            int rr = blockIdx.x * 64 + wid * 16 + kgrp * 4 + jj;
            float val = fmaxf(acc2[nt][jj] + bb, 0.f) * sv + tv;
            if (rr < M) {
                out[(size_t)rr * 128 + col] = val;
                hbout[(size_t)rr * 128 + col] = (unsigned short)f2bf(val);
            }
        }
    }
}

// ---------------------------------------------------------------- fused L3+head
// out[r] = dot(relu( bn(relu( relu(A@W3a+b3a) @ W3b + b3b )) @ Wl + bl ), Wf) + bf
// 256 threads, 64 rows/block, 3 GEMM stages through LDS hi/lo planes.
__global__ __launch_bounds__(256)
void fused3_kernel(const float* __restrict__ A,
                   const short* __restrict__ P1, const float* __restrict__ bias1,
                   const short* __restrict__ P2, const float* __restrict__ bias2,
                   const float* __restrict__ g, const float* __restrict__ be,
                   const float* __restrict__ m, const float* __restrict__ v,
                   const short* __restrict__ Pl, const float* __restrict__ bl,
                   const float* __restrict__ Wf, const float* __restrict__ bf,
                   float* __restrict__ out, int M) {
    constexpr int T  = 4 * 8 * 64;
    constexpr int LDW = 136;
    __shared__ short h1hi[64 * LDW];
    __shared__ short h1lo[64 * LDW];

    const int tid  = threadIdx.x;
    const int wid  = tid >> 6;
    const int lane = tid & 63;
    const int rlo  = lane & 15;
    const int kgrp = lane >> 4;

    const int row = blockIdx.x * 64 + wid * 16 + rlo;
    const int r   = row < M ? row : M - 1;
    const float* arow = A + (size_t)r * 128 + kgrp * 8;

    const bf16x8* P1v = (const bf16x8*)P1;
    const bf16x8* P2v = (const bf16x8*)P2;
    const bf16x8* Plv = (const bf16x8*)Pl;

    // ---- stage 1: relu(A@W3a + b3a) -> LDS
    f32x4 acc[8];
    #pragma unroll
    for (int i = 0; i < 8; ++i) acc[i] = (f32x4)0.0f;
    #pragma unroll
    for (int c = 0; c < 4; ++c) {
        f32x4 a0 = *(const f32x4*)(arow + c * 32);
        f32x4 a1 = *(const f32x4*)(arow + c * 32 + 4);
        bf16x8 ah, al;
        #pragma unroll
        for (int j = 0; j < 4; ++j) {
            short h0 = f2bf(a0[j]);
            short h1 = f2bf(a1[j]);
            ah[j]     = h0;
            ah[j + 4] = h1;
            al[j]     = f2bf(a0[j] - bf2f(h0));
            al[j + 4] = f2bf(a1[j] - bf2f(h1));
        }
        #pragma unroll
        for (int nt = 0; nt < 8; ++nt) {
            int fi = ((c * 8) + nt) * 64 + lane;
            bf16x8 wh = P1v[fi];
            bf16x8 wl = P1v[T + fi];
            acc[nt] = __builtin_amdgcn_mfma_f32_16x16x32_bf16(ah, wh, acc[nt], 0, 0, 0);
            acc[nt] = __builtin_amdgcn_mfma_f32_16x16x32_bf16(al, wh, acc[nt], 0, 0, 0);
            acc[nt] = __builtin_amdgcn_mfma_f32_16x16x32_bf16(ah, wl, acc[nt], 0, 0, 0);
        }
    }
    #pragma unroll
    for (int nt = 0; nt < 8; ++nt) {
        int col  = nt * 16 + rlo;
        float bb = bias1[col];
        #pragma unroll
        for (int jj = 0; jj < 4; ++jj) {
            int lr = wid * 16 + kgrp * 4 + jj;
            float val = fmaxf(acc[nt][jj] + bb, 0.f);
            short h = f2bf(val);
            h1hi[lr * LDW + col] = h;
            h1lo[lr * LDW + col] = f2bf(val - bf2f(h));
        }
    }
    __syncthreads();

    // ---- stage 2: bn(relu(h1@W3b + b3b)) -> LDS (reuse planes)
    const int lr2 = wid * 16 + rlo;
    bf16x8 ah2[4], al2[4];
    #pragma unroll
    for (int c = 0; c < 4; ++c) {
        ah2[c] = *(bf16x8*)&h1hi[lr2 * LDW + c * 32 + kgrp * 8];
        al2[c] = *(bf16x8*)&h1lo[lr2 * LDW + c * 32 + kgrp * 8];
    }
    __syncthreads();   // all reads done before overwrite
    f32x4 acc2[8];
    #pragma unroll
    for (int i = 0; i < 8; ++i) acc2[i] = (f32x4)0.0f;
    #pragma unroll
    for (int c = 0; c < 4; ++c) {
        #pragma unroll
        for (int nt = 0; nt < 8; ++nt) {
            int fi = ((c * 8) + nt) * 64 + lane;
            bf16x8 wh = P2v[fi];
            bf16x8 wl = P2v[T + fi];
            acc2[nt] = __builtin_amdgcn_mfma_f32_16x16x32_bf16(ah2[c], wh, acc2[nt], 0, 0, 0);
            acc2[nt] = __builtin_amdgcn_mfma_f32_16x16x32_bf16(al2[c], wh, acc2[nt], 0, 0, 0);
            acc2[nt] = __builtin_amdgcn_mfma_f32_16x16x32_bf16(ah2[c], wl, acc2[nt], 0, 0, 0);
        }
    }
    #pragma unroll
    for (int nt = 0; nt < 8; ++nt) {
        int col  = nt * 16 + rlo;
        float bb = bias2[col];
        float sv = g[col] * rsqrtf(v[col] + 1e-5f);
        float tv = be[col] - m[col] * sv;
        #pragma unroll
        for (int jj = 0; jj < 4; ++jj) {
            int lr = wid * 16 + kgrp * 4 + jj;
            float val = fmaxf(acc2[nt][jj] + bb, 0.f) * sv + tv;
            short h = f2bf(val);
            h1hi[lr * LDW + col] = h;
            h1lo[lr * LDW + col] = f2bf(val - bf2f(h));
        }
    }
    __syncthreads();

    // ---- stage 3: relu(h2@Wl + bl) . Wf + bf -> out
    bf16x8 ah3[4], al3[4];
    #pragma unroll
    for (int c = 0; c < 4; ++c) {
        ah3[c] = *(bf16x8*)&h1hi[lr2 * LDW + c * 32 + kgrp * 8];
        al3[c] = *(bf16x8*)&h1lo[lr2 * LDW + c * 32 + kgrp * 8];
    }
    f32x4 acc3[8];
    #pragma unroll
    for (int i = 0; i < 8; ++i) acc3[i] = (f32x4)0.0f;
    #pragma unroll
    for (int c = 0; c < 4; ++c) {
        #pragma unroll
        for (int nt = 0; nt < 8; ++nt) {
            int fi = ((c * 8) + nt) * 64 + lane;
            bf16x8 wh = Plv[fi];
            bf16x8 wl = Plv[T + fi];
            acc3[nt] = __builtin_amdgcn_mfma_f32_16x16x32_bf16(ah3[c], wh, acc3[nt], 0, 0, 0);
            acc3[nt] = __builtin_amdgcn_mfma_f32_16x16x32_bf16(al3[c], wh, acc3[nt], 0, 0, 0);
            acc3[nt] = __builtin_amdgcn_mfma_f32_16x16x32_bf16(ah3[c], wl, acc3[nt], 0, 0, 0);
        }
    }
    float p0 = 0, p1 = 0, p2 = 0, p3 = 0;
    #pragma unroll
    for (int nt = 0; nt < 8; ++nt) {
        int col  = nt * 16 + rlo;
        float bb = bl[col];
        float wv = Wf[col];
        p0 += fmaxf(acc3[nt][0] + bb, 0.f) * wv;
        p1 += fmaxf(acc3[nt][1] + bb, 0.f) * wv;
        p2 += fmaxf(acc3[nt][2] + bb, 0.f) * wv;
        p3 += fmaxf(acc3[nt][3] + bb, 0.f) * wv;
    }
    #pragma unroll
    for (int o = 1; o < 16; o <<= 1) {
        p0 += __shfl_xor(p0, o);
        p1 += __shfl_xor(p1, o);
        p2 += __shfl_xor(p2, o);
        p3 += __shfl_xor(p3, o);
    }
    if (rlo == 0) {
        int rbase = blockIdx.x * 64 + wid * 16 + kgrp * 4;
        float bfv = bf[0];
        if (rbase + 0 < M) out[rbase + 0] = p0 + bfv;
        if (rbase + 1 < M) out[rbase + 1] = p1 + bfv;
        if (rbase + 2 < M) out[rbase + 2] = p2 + bfv;
        if (rbase + 3 < M) out[rbase + 3] = p3 + bfv;
    }
}

// ---------------------------------------------------------------------------
extern "C" void kernel_launch(void* const* d_in, const int* in_sizes, int n_in,
                              void* d_out, int out_size, void* d_ws, size_t ws_size,
                              hipStream_t stream) {
    const float* x    = (const float*)d_in[0];
    const int*   eidx = (const int*)d_in[1];
    const float* eps1 = (const float*)d_in[2];
    const float* W1a  = (const float*)d_in[3];
    const float* b1a  = (const float*)d_in[4];
    const float* W1b  = (const float*)d_in[5];
    const float* b1b  = (const float*)d_in[6];
    const float* g1   = (const float*)d_in[7];
    const float* be1  = (const float*)d_in[8];
    const float* m1   = (const float*)d_in[9];
    const float* v1   = (const float*)d_in[10];
    const float* eps2 = (const float*)d_in[11];
    const float* W2a  = (const float*)d_in[12];
    const float* b2a  = (const float*)d_in[13];
    const float* g2   = (const float*)d_in[14];
    const float* be2  = (const float*)d_in[15];
    const float* m2   = (const float*)d_in[16];
    const float* v2   = (const float*)d_in[17];
    const float* eps3 = (const float*)d_in[18];
    const float* W3a  = (const float*)d_in[19];
    const float* b3a  = (const float*)d_in[20];
    const float* W3b  = (const float*)d_in[21];
    const float* b3b  = (const float*)d_in[22];
    const float* g3   = (const float*)d_in[23];
    const float* be3  = (const float*)d_in[24];
    const float* m3   = (const float*)d_in[25];
    const float* v3   = (const float*)d_in[26];
    const float* Wl   = (const float*)d_in[27];
    const float* bl   = (const float*)d_in[28];
    const float* Wf   = (const float*)d_in[29];
    const float* bfp  = (const float*)d_in[30];

    char* ws = (char*)d_ws;
    size_t off = 0;
    auto alloc = [&](size_t bytes) -> void* {
        off = (off + 255) & ~(size_t)255;
        void* p = ws + off;
        off += bytes;
        return p;
    };

    float*          bufA = (float*)alloc((size_t)NN * 128 * 4);
    float*          bufB = (float*)alloc((size_t)NN * 128 * 4);
    unsigned short* hb   = (unsigned short*)alloc((size_t)NN * 128 * 2);
    int*   deg    = (int*)alloc((size_t)NN * 4);
    int*   offs   = (int*)alloc((size_t)(NN + 1) * 4);
    int*   cursor = (int*)alloc((size_t)NN * 4);
    int*   esrc   = (int*)alloc((size_t)NE * 4);
    int*   bsum   = (int*)alloc(256 * 4);
    short* P1a    = (short*)alloc((size_t)2 * DIN * HID * 2);
    short* P1b    = (short*)alloc((size_t)2 * HID * HID * 2);
    short* P2a    = (short*)alloc((size_t)2 * HID * HID * 2);
    short* P3a    = (short*)alloc((size_t)2 * HID * HID * 2);
    short* P3b    = (short*)alloc((size_t)2 * HID * HID * 2);
    short* Pl     = (short*)alloc((size_t)2 * HID * HID * 2);

    const int NB_SCAN = (NN + 511) / 512;           // 196
    const int GRID_E  = (NE + 255) / 256;           // 6250
    const int GRID_G  = (NN + 127) / 128;           // 782  (gemm_bn, 128 rows)
    const int GRID_F  = (NN + 63) / 64;             // 1563 (fused, 64 rows)
    const int GRID_A64  = (NN + 31) / 32;           // aggb<64>: 32 nodes/block
    const int GRID_A128 = (NN + 15) / 16;           // aggb<128>: 16 nodes/block

    // ---- CSR build
    hipMemsetAsync(deg, 0, (size_t)NN * 4, stream);
    hist_kernel<<<GRID_E, 256, 0, stream>>>(eidx, deg);
    scan1_kernel<<<NB_SCAN, 512, 0, stream>>>(deg, offs, bsum);
    scan2_kernel<<<1, 256, 0, stream>>>(bsum, NB_SCAN);
    scan3_kernel<<<NB_SCAN, 512, 0, stream>>>(offs, bsum, cursor);
    scatter_kernel<<<GRID_E, 256, 0, stream>>>(eidx, cursor, esrc);

    // ---- pack weights + bf16 x
    {
        dim3 grid(8, 6);
        packall_kernel<<<grid, 256, 0, stream>>>(W1a, W1b, W2a, W3a, W3b, Wl,
                                                 P1a, P1b, P2a, P3a, P3b, Pl);
    }
    cvt_kernel<<<(NN * DIN / 8 + 255) / 256, 256, 0, stream>>>(x, hb);

    // ---- layer 1 (agg -> fused W1a+W1b+BN)
    aggb_kernel<64><<<GRID_A64, 256, 0, stream>>>(x, hb, offs, esrc, eps1, bufA);
    fused2_kernel<64><<<GRID_F, 256, 0, stream>>>(bufA, P1a, b1a, P1b, b1b,
                                                  g1, be1, m1, v1, bufB, hb, NN);
    // ---- layer 2 (agg -> single GEMM+BN)
    aggb_kernel<128><<<GRID_A128, 256, 0, stream>>>(bufB, hb, offs, esrc, eps2, bufA);
    gemm_bn_kernel<<<GRID_G, 512, 0, stream>>>(bufA, P2a, b2a, g2, be2, m2, v2,
                                               bufB, hb, NN);
    // ---- layer 3 + head (agg -> fused W3a+W3b+BN+Wl+Wf)
    aggb_kernel<128><<<GRID_A128, 256, 0, stream>>>(bufB, hb, offs, esrc, eps3, bufA);
    fused3_kernel<<<GRID_F, 256, 0, stream>>>(bufA, P3a, b3a, P3b, b3b,
                                              g3, be3, m3, v3, Pl, bl, Wf, bfp,
                                              (float*)d_out, NN);
}

// Round 6
// 388.302 us; speedup vs baseline: 2.2809x; 1.3678x over previous
//
#include <hip/hip_runtime.h>

// ---------------------------------------------------------------------------
// GIN forward on MI355X.
// CSR build (2-level counting sort, write-amp ~1) ->
//   [agg (bf16 gather) -> GEMM bf16x3] x3, layer1 pair fused,
//   layer3 pair + head fused.
// ---------------------------------------------------------------------------

constexpr int NN  = 100000;   // nodes
constexpr int NE  = 1600000;  // edges
constexpr int DIN = 64;
constexpr int HID = 128;

constexpr int BSH   = 9;      // 512 dsts per bucket
constexpr int NBUCK = 196;    // ceil(NN / 512)
constexpr int NBLK  = 200;    // partition blocks
constexpr int CHUNK = 8000;   // NE / NBLK

typedef __attribute__((ext_vector_type(4))) float f32x4;
typedef __attribute__((ext_vector_type(8))) short bf16x8;
typedef __attribute__((ext_vector_type(8))) unsigned short u16x8;

__device__ __forceinline__ short f2bf(float f) {
    union { float f; unsigned u; } x; x.f = f;
    unsigned r = x.u + 0x7fffu + ((x.u >> 16) & 1u);   // RNE
    return (short)(r >> 16);
}
__device__ __forceinline__ float bf2f(short s) {
    union { unsigned u; float f; } x; x.u = ((unsigned)(unsigned short)s) << 16;
    return x.f;
}

// ---------------------------------------------------------------- CSR build
// A: per-block LDS histogram over buckets; reserve block slices via one
//    global atomic per (block,bucket).
__global__ __launch_bounds__(256)
void bhist_kernel(const int* __restrict__ eidx, int* __restrict__ bcnt,
                  int* __restrict__ pbase) {
    __shared__ int lh[NBUCK];
    int b = blockIdx.x;
    for (int i = threadIdx.x; i < NBUCK; i += 256) lh[i] = 0;
    __syncthreads();
    int e0 = b * CHUNK;
    for (int i = threadIdx.x; i < CHUNK; i += 256)
        atomicAdd(&lh[eidx[NE + e0 + i] >> BSH], 1);
    __syncthreads();
    for (int i = threadIdx.x; i < NBUCK; i += 256)
        pbase[b * NBUCK + i] = atomicAdd(&bcnt[i], lh[i]);
}

// B: exclusive scan of bucket counts -> bucket bases.
__global__ void bscan_kernel(const int* __restrict__ bcnt, int* __restrict__ bbase,
                             int* __restrict__ offs) {
    __shared__ int lds[256];
    int t = threadIdx.x;
    int v = (t < NBUCK) ? bcnt[t] : 0;
    lds[t] = v; __syncthreads();
    #pragma unroll
    for (int o = 1; o < 256; o <<= 1) {
        int x = (t >= o) ? lds[t - o] : 0;
        __syncthreads();
        lds[t] += x;
        __syncthreads();
    }
    if (t < NBUCK) bbase[t] = lds[t] - v;
    if (t == 0) { bbase[NBUCK] = NE; offs[NN] = NE; }
}

// C: partition edges into bucket-contiguous tmp, LDS-staged for coalescing.
__global__ __launch_bounds__(256)
void part_kernel(const int* __restrict__ eidx, const int* __restrict__ bbase,
                 const int* __restrict__ pbase, int2* __restrict__ tmp) {
    __shared__ int lh[NBUCK], lofs[NBUCK], lcnt[NBUCK], gb[NBUCK];
    __shared__ int sb[256];
    __shared__ int2 lp[CHUNK];
    int b = blockIdx.x;
    int t = threadIdx.x;
    for (int i = t; i < NBUCK; i += 256) { lh[i] = 0; lcnt[i] = 0; }
    __syncthreads();
    int e0 = b * CHUNK;
    for (int i = t; i < CHUNK; i += 256)
        atomicAdd(&lh[eidx[NE + e0 + i] >> BSH], 1);
    __syncthreads();
    {   // exclusive scan lh -> lofs; fetch global bases
        int v = (t < NBUCK) ? lh[t] : 0;
        sb[t] = v; __syncthreads();
        #pragma unroll
        for (int o = 1; o < 256; o <<= 1) {
            int x = (t >= o) ? sb[t - o] : 0;
            __syncthreads();
            sb[t] += x;
            __syncthreads();
        }
        if (t < NBUCK) {
            lofs[t] = sb[t] - v;
            gb[t]   = bbase[t] + pbase[b * NBUCK + t];
        }
    }
    __syncthreads();
    for (int i = t; i < CHUNK; i += 256) {
        int s = eidx[e0 + i], d = eidx[NE + e0 + i];
        int bk = d >> BSH;
        int r = atomicAdd(&lcnt[bk], 1);
        lp[lofs[bk] + r] = int2{s, d};
    }
    __syncthreads();
    for (int i = t; i < CHUNK; i += 256) {
        int2 p = lp[i];
        int bk = p.y >> BSH;
        tmp[gb[bk] + (i - lofs[bk])] = p;   // consecutive i -> consecutive addr
    }
}

// D: per-bucket counting sort -> offs + esrc (writes confined to 32KB window).
__global__ __launch_bounds__(512)
void bsort_kernel(const int* __restrict__ bbase, const int2* __restrict__ tmp,
                  int* __restrict__ offs, int* __restrict__ esrc) {
    __shared__ int h[512], lo[512], cnt[512];
    int bk = blockIdx.x;
    int n0 = bk << BSH;
    int lo0 = bbase[bk], hi0 = bbase[bk + 1];
    int t = threadIdx.x;
    h[t] = 0; cnt[t] = 0;
    __syncthreads();
    for (int i = lo0 + t; i < hi0; i += 512)
        atomicAdd(&h[tmp[i].y - n0], 1);
    __syncthreads();
    int v = h[t];
    lo[t] = v; __syncthreads();
    #pragma unroll
    for (int o = 1; o < 512; o <<= 1) {
        int x = (t >= o) ? lo[t - o] : 0;
        __syncthreads();
        lo[t] += x;
        __syncthreads();
    }
    int excl = lo[t] - v;
    __syncthreads();
    lo[t] = excl;
    __syncthreads();
    if (n0 + t < NN) offs[n0 + t] = lo0 + excl;
    for (int i = lo0 + t; i < hi0; i += 512) {
        int2 p = tmp[i];
        int ld = p.y - n0;
        int r = atomicAdd(&cnt[ld], 1);
        esrc[lo0 + lo[ld] + r] = p.x;
    }
}

// ---------------------------------------------------------------- x -> bf16
__global__ void cvt_kernel(const float* __restrict__ x, unsigned short* __restrict__ xb) {
    int i = blockIdx.x * 256 + threadIdx.x;       // ushort8 index
    if (i >= NN * DIN / 8) return;
    const f32x4* p = (const f32x4*)x + (size_t)i * 2;
    f32x4 v0 = p[0], v1 = p[1];
    u16x8 o;
    #pragma unroll
    for (int j = 0; j < 4; ++j) {
        o[j]     = (unsigned short)f2bf(v0[j]);
        o[j + 4] = (unsigned short)f2bf(v1[j]);
    }
    ((u16x8*)xb)[i] = o;
}

// ---------------------------------------------------------------- aggregation
// out[n] = (1+eps)*hf[n] + sum_{s in nbr(n)} hb[s]
template<int D>
__global__ __launch_bounds__(256)
void aggb_kernel(const float* __restrict__ hf, const unsigned short* __restrict__ hb,
                 const int* __restrict__ offs, const int* __restrict__ esrc,
                 const float* __restrict__ epsp, float* __restrict__ out) {
    constexpr int TPN = D / 8;                 // lanes per node (ushort8 each)
    int node = blockIdx.x * (256 / TPN) + threadIdx.x / TPN;
    int f    = threadIdx.x % TPN;
    if (node >= NN) return;
    const u16x8* h8 = (const u16x8*)hb;
    float eps = 1.0f + *epsp;

    const float* hrow = hf + (size_t)node * D + f * 8;
    f32x4 a0 = *(const f32x4*)hrow * eps;
    f32x4 a1 = *(const f32x4*)(hrow + 4) * eps;
    f32x4 b0 = (f32x4)0.f, b1 = (f32x4)0.f;

    union { unsigned u; float fv; } cvt;
    auto acc8 = [&](u16x8 t, f32x4& x0, f32x4& x1) {
        #pragma unroll
        for (int j = 0; j < 4; ++j) { cvt.u = ((unsigned)t[j]) << 16;     x0[j] += cvt.fv; }
        #pragma unroll
        for (int j = 0; j < 4; ++j) { cvt.u = ((unsigned)t[j + 4]) << 16; x1[j] += cvt.fv; }
    };

    int k = offs[node], k1 = offs[node + 1];
    for (; k + 8 <= k1; k += 8) {
        int s0 = esrc[k+0], s1 = esrc[k+1], s2 = esrc[k+2], s3 = esrc[k+3];
        int s4 = esrc[k+4], s5 = esrc[k+5], s6 = esrc[k+6], s7 = esrc[k+7];
        u16x8 t0 = h8[(size_t)s0*TPN+f], t1 = h8[(size_t)s1*TPN+f];
        u16x8 t2 = h8[(size_t)s2*TPN+f], t3 = h8[(size_t)s3*TPN+f];
        u16x8 t4 = h8[(size_t)s4*TPN+f], t5 = h8[(size_t)s5*TPN+f];
        u16x8 t6 = h8[(size_t)s6*TPN+f], t7 = h8[(size_t)s7*TPN+f];
        acc8(t0, a0, a1); acc8(t1, b0, b1); acc8(t2, a0, a1); acc8(t3, b0, b1);
        acc8(t4, a0, a1); acc8(t5, b0, b1); acc8(t6, a0, a1); acc8(t7, b0, b1);
    }
    for (; k + 2 <= k1; k += 2) {
        u16x8 t0 = h8[(size_t)esrc[k]*TPN+f];
        u16x8 t1 = h8[(size_t)esrc[k+1]*TPN+f];
        acc8(t0, a0, a1); acc8(t1, b0, b1);
    }
    if (k < k1) acc8(h8[(size_t)esrc[k]*TPN+f], a0, a1);

    float* orow = out + (size_t)node * D + f * 8;
    *(f32x4*)orow       = a0 + b0;
    *(f32x4*)(orow + 4) = a1 + b1;
}

// ---------------------------------------------------------------- weight pack
// frag: P[c][nt][lane][j] = bf16( W[c*32 + (lane>>4)*8 + j][nt*16 + (lane&15)] )
__global__ void packall_kernel(const float* __restrict__ W1a, const float* __restrict__ W1b,
                               const float* __restrict__ W2a, const float* __restrict__ W3a,
                               const float* __restrict__ W3b, const float* __restrict__ Wl,
                               short* P1a, short* P1b, short* P2a,
                               short* P3a, short* P3b, short* Pl) {
    const float* W; short* P; int K;
    switch (blockIdx.y) {
        case 0: W = W1a; P = P1a; K = 64;  break;
        case 1: W = W1b; P = P1b; K = 128; break;
        case 2: W = W2a; P = P2a; K = 128; break;
        case 3: W = W3a; P = P3a; K = 128; break;
        case 4: W = W3b; P = P3b; K = 128; break;
        default: W = Wl; P = Pl;  K = 128; break;
    }
    int T = (K / 32) * 8 * 64;
    int idx = blockIdx.x * 256 + threadIdx.x;
    if (idx >= T) return;
    int c  = idx >> 9;
    int nt = (idx >> 6) & 7;
    int l  = idx & 63;
    int col   = nt * 16 + (l & 15);
    int kbase = c * 32 + (l >> 4) * 8;
    bf16x8 hi, lo;
    #pragma unroll
    for (int j = 0; j < 8; ++j) {
        float w = W[(kbase + j) * HID + col];
        short h = f2bf(w);
        hi[j] = h;
        lo[j] = f2bf(w - bf2f(h));
    }
    *(bf16x8*)&P[(size_t)idx * 8]       = hi;
    *(bf16x8*)&P[(size_t)(T + idx) * 8] = lo;
}

// ---------------------------------------------------------------- single GEMM
// out = bn(relu(A@W + bias)); also writes bf16 copy hbout. 512 thr, 128 rows.
__global__ __launch_bounds__(512)
void gemm_bn_kernel(const float* __restrict__ A, const short* __restrict__ P,
                    const float* __restrict__ bias,
                    const float* __restrict__ g, const float* __restrict__ be,
                    const float* __restrict__ m, const float* __restrict__ v,
                    float* __restrict__ out, unsigned short* __restrict__ hbout, int M) {
    constexpr int NCH = 4;
    constexpr int T   = NCH * 8 * 64;
    __shared__ short wlds[2 * T * 8];

    const int tid  = threadIdx.x;
    const int wid  = tid >> 6;
    const int lane = tid & 63;

    for (int i = tid; i < 2 * T; i += 512)
        ((bf16x8*)wlds)[i] = ((const bf16x8*)P)[i];
    __syncthreads();

    const int rlo  = lane & 15;
    const int kgrp = lane >> 4;
    const int row  = blockIdx.x * 128 + wid * 16 + rlo;
    const int r    = row < M ? row : M - 1;
    const float* arow = A + (size_t)r * 128 + kgrp * 8;

    f32x4 acc[8];
    #pragma unroll
    for (int i = 0; i < 8; ++i) acc[i] = (f32x4)0.0f;

    #pragma unroll
    for (int c = 0; c < NCH; ++c) {
        f32x4 a0 = *(const f32x4*)(arow + c * 32);
        f32x4 a1 = *(const f32x4*)(arow + c * 32 + 4);
        bf16x8 ah, al;
        #pragma unroll
        for (int j = 0; j < 4; ++j) {
            short h0 = f2bf(a0[j]);
            short h1 = f2bf(a1[j]);
            ah[j]     = h0;
            ah[j + 4] = h1;
            al[j]     = f2bf(a0[j] - bf2f(h0));
            al[j + 4] = f2bf(a1[j] - bf2f(h1));
        }
        #pragma unroll
        for (int nt = 0; nt < 8; ++nt) {
            int fi = ((c * 8) + nt) * 64 + lane;
            bf16x8 wh = *(bf16x8*)&wlds[(size_t)fi * 8];
            bf16x8 wl = *(bf16x8*)&wlds[(size_t)(T + fi) * 8];
            acc[nt] = __builtin_amdgcn_mfma_f32_16x16x32_bf16(ah, wh, acc[nt], 0, 0, 0);
            acc[nt] = __builtin_amdgcn_mfma_f32_16x16x32_bf16(al, wh, acc[nt], 0, 0, 0);
            acc[nt] = __builtin_amdgcn_mfma_f32_16x16x32_bf16(ah, wl, acc[nt], 0, 0, 0);
        }
    }

    #pragma unroll
    for (int nt = 0; nt < 8; ++nt) {
        int col  = nt * 16 + rlo;
        float bb = bias[col];
        float sv = g[col] * rsqrtf(v[col] + 1e-5f);
        float tv = be[col] - m[col] * sv;
        #pragma unroll
        for (int jj = 0; jj < 4; ++jj) {
            int rr = blockIdx.x * 128 + wid * 16 + kgrp * 4 + jj;
            float val = fmaxf(acc[nt][jj] + bb, 0.f) * sv + tv;
            if (rr < M) {
                out[(size_t)rr * 128 + col] = val;
                hbout[(size_t)rr * 128 + col] = (unsigned short)f2bf(val);
            }
        }
    }
}

// ---------------------------------------------------------------- fused pair
// out = bn(relu( relu(A@W1 + b1) @ W2 + b2 ));  bf16 copy to hbout.
template<int K1>
__global__ __launch_bounds__(256)
void fused2_kernel(const float* __restrict__ A,
                   const short* __restrict__ P1, const float* __restrict__ bias1,
                   const short* __restrict__ P2, const float* __restrict__ bias2,
                   const float* __restrict__ g, const float* __restrict__ be,
                   const float* __restrict__ m, const float* __restrict__ v,
                   float* __restrict__ out, unsigned short* __restrict__ hbout, int M) {
    constexpr int NCH1 = K1 / 32;
    constexpr int T1   = NCH1 * 8 * 64;
    constexpr int T2   = 4 * 8 * 64;
    constexpr int LDW  = 136;
    __shared__ short h1hi[64 * LDW];
    __shared__ short h1lo[64 * LDW];

    const int tid  = threadIdx.x;
    const int wid  = tid >> 6;
    const int lane = tid & 63;
    const int rlo  = lane & 15;
    const int kgrp = lane >> 4;

    const int row = blockIdx.x * 64 + wid * 16 + rlo;
    const int r   = row < M ? row : M - 1;
    const float* arow = A + (size_t)r * K1 + kgrp * 8;

    const bf16x8* P1v = (const bf16x8*)P1;
    const bf16x8* P2v = (const bf16x8*)P2;

    f32x4 acc[8];
    #pragma unroll
    for (int i = 0; i < 8; ++i) acc[i] = (f32x4)0.0f;

    #pragma unroll
    for (int c = 0; c < NCH1; ++c) {
        f32x4 a0 = *(const f32x4*)(arow + c * 32);
        f32x4 a1 = *(const f32x4*)(arow + c * 32 + 4);
        bf16x8 ah, al;
        #pragma unroll
        for (int j = 0; j < 4; ++j) {
            short h0 = f2bf(a0[j]);
            short h1 = f2bf(a1[j]);
            ah[j]     = h0;
            ah[j + 4] = h1;
            al[j]     = f2bf(a0[j] - bf2f(h0));
            al[j + 4] = f2bf(a1[j] - bf2f(h1));
        }
        #pragma unroll
        for (int nt = 0; nt < 8; ++nt) {
            int fi = ((c * 8) + nt) * 64 + lane;
            bf16x8 wh = P1v[fi];
            bf16x8 wl = P1v[T1 + fi];
            acc[nt] = __builtin_amdgcn_mfma_f32_16x16x32_bf16(ah, wh, acc[nt], 0, 0, 0);
            acc[nt] = __builtin_amdgcn_mfma_f32_16x16x32_bf16(al, wh, acc[nt], 0, 0, 0);
            acc[nt] = __builtin_amdgcn_mfma_f32_16x16x32_bf16(ah, wl, acc[nt], 0, 0, 0);
        }
    }

    #pragma unroll
    for (int nt = 0; nt < 8; ++nt) {
        int col  = nt * 16 + rlo;
        float bb = bias1[col];
        #pragma unroll
        for (int jj = 0; jj < 4; ++jj) {
            int lr = wid * 16 + kgrp * 4 + jj;
            float val = fmaxf(acc[nt][jj] + bb, 0.f);
            short h = f2bf(val);
            h1hi[lr * LDW + col] = h;
            h1lo[lr * LDW + col] = f2bf(val - bf2f(h));
        }
    }
    __syncthreads();

    f32x4 acc2[8];
    #pragma unroll
    for (int i = 0; i < 8; ++i) acc2[i] = (f32x4)0.0f;
    const int lr2 = wid * 16 + rlo;
    #pragma unroll
    for (int c = 0; c < 4; ++c) {
        bf16x8 ah = *(bf16x8*)&h1hi[lr2 * LDW + c * 32 + kgrp * 8];
        bf16x8 al = *(bf16x8*)&h1lo[lr2 * LDW + c * 32 + kgrp * 8];
        #pragma unroll
        for (int nt = 0; nt < 8; ++nt) {
            int fi = ((c * 8) + nt) * 64 + lane;
            bf16x8 wh = P2v[fi];
            bf16x8 wl = P2v[T2 + fi];
            acc2[nt] = __builtin_amdgcn_mfma_f32_16x16x32_bf16(ah, wh, acc2[nt], 0, 0, 0);
            acc2[nt] = __builtin_amdgcn_mfma_f32_16x16x32_bf16(al, wh, acc2[nt], 0, 0, 0);
            acc2[nt] = __builtin_amdgcn_mfma_f32_16x16x32_bf16(ah, wl, acc2[nt], 0, 0, 0);
        }
    }

    #pragma unroll
    for (int nt = 0; nt < 8; ++nt) {
        int col  = nt * 16 + rlo;
        float bb = bias2[col];
        float sv = g[col] * rsqrtf(v[col] + 1e-5f);
        float tv = be[col] - m[col] * sv;
        #pragma unroll
        for (int jj = 0; jj < 4; ++jj) {
            int rr = blockIdx.x * 64 + wid * 16 + kgrp * 4 + jj;
            float val = fmaxf(acc2[nt][jj] + bb, 0.f) * sv + tv;
            if (rr < M) {
                out[(size_t)rr * 128 + col] = val;
                hbout[(size_t)rr * 128 + col] = (unsigned short)f2bf(val);
            }
        }
    }
}

// ---------------------------------------------------------------- fused L3+head
// out[r] = dot(relu( bn(relu( relu(A@W3a+b3a) @ W3b + b3b )) @ Wl + bl ), Wf) + bf
__global__ __launch_bounds__(256)
void fused3_kernel(const float* __restrict__ A,
                   const short* __restrict__ P1, const float* __restrict__ bias1,
                   const short* __restrict__ P2, const float* __restrict__ bias2,
                   const float* __restrict__ g, const float* __restrict__ be,
                   const float* __restrict__ m, const float* __restrict__ v,
                   const short* __restrict__ Pl, const float* __restrict__ bl,
                   const float* __restrict__ Wf, const float* __restrict__ bf,
                   float* __restrict__ out, int M) {
    constexpr int T  = 4 * 8 * 64;
    constexpr int LDW = 136;
    __shared__ short h1hi[64 * LDW];
    __shared__ short h1lo[64 * LDW];

    const int tid  = threadIdx.x;
    const int wid  = tid >> 6;
    const int lane = tid & 63;
    const int rlo  = lane & 15;
    const int kgrp = lane >> 4;

    const int row = blockIdx.x * 64 + wid * 16 + rlo;
    const int r   = row < M ? row : M - 1;
    const float* arow = A + (size_t)r * 128 + kgrp * 8;

    const bf16x8* P1v = (const bf16x8*)P1;
    const bf16x8* P2v = (const bf16x8*)P2;
    const bf16x8* Plv = (const bf16x8*)Pl;

    f32x4 acc[8];
    #pragma unroll
    for (int i = 0; i < 8; ++i) acc[i] = (f32x4)0.0f;
    #pragma unroll
    for (int c = 0; c < 4; ++c) {
        f32x4 a0 = *(const f32x4*)(arow + c * 32);
        f32x4 a1 = *(const f32x4*)(arow + c * 32 + 4);
        bf16x8 ah, al;
        #pragma unroll
        for (int j = 0; j < 4; ++j) {
            short h0 = f2bf(a0[j]);
            short h1 = f2bf(a1[j]);
            ah[j]     = h0;
            ah[j + 4] = h1;
            al[j]     = f2bf(a0[j] - bf2f(h0));
            al[j + 4] = f2bf(a1[j] - bf2f(h1));
        }
        #pragma unroll
        for (int nt = 0; nt < 8; ++nt) {
            int fi = ((c * 8) + nt) * 64 + lane;
            bf16x8 wh = P1v[fi];
            bf16x8 wl = P1v[T + fi];
            acc[nt] = __builtin_amdgcn_mfma_f32_16x16x32_bf16(ah, wh, acc[nt], 0, 0, 0);
            acc[nt] = __builtin_amdgcn_mfma_f32_16x16x32_bf16(al, wh, acc[nt], 0, 0, 0);
            acc[nt] = __builtin_amdgcn_mfma_f32_16x16x32_bf16(ah, wl, acc[nt], 0, 0, 0);
        }
    }
    #pragma unroll
    for (int nt = 0; nt < 8; ++nt) {
        int col  = nt * 16 + rlo;
        float bb = bias1[col];
        #pragma unroll
        for (int jj = 0; jj < 4; ++jj) {
            int lr = wid * 16 + kgrp * 4 + jj;
            float val = fmaxf(acc[nt][jj] + bb, 0.f);
            short h = f2bf(val);
            h1hi[lr * LDW + col] = h;
            h1lo[lr * LDW + col] = f2bf(val - bf2f(h));
        }
    }
    __syncthreads();

    const int lr2 = wid * 16 + rlo;
    bf16x8 ah2[4], al2[4];
    #pragma unroll
    for (int c = 0; c < 4; ++c) {
        ah2[c] = *(bf16x8*)&h1hi[lr2 * LDW + c * 32 + kgrp * 8];
        al2[c] = *(bf16x8*)&h1lo[lr2 * LDW + c * 32 + kgrp * 8];
    }
    __syncthreads();
    f32x4 acc2[8];
    #pragma unroll
    for (int i = 0; i < 8; ++i) acc2[i] = (f32x4)0.0f;
    #pragma unroll
    for (int c = 0; c < 4; ++c) {
        #pragma unroll
        for (int nt = 0; nt < 8; ++nt) {
            int fi = ((c * 8) + nt) * 64 + lane;
            bf16x8 wh = P2v[fi];
            bf16x8 wl = P2v[T + fi];
            acc2[nt] = __builtin_amdgcn_mfma_f32_16x16x32_bf16(ah2[c], wh, acc2[nt], 0, 0, 0);
            acc2[nt] = __builtin_amdgcn_mfma_f32_16x16x32_bf16(al2[c], wh, acc2[nt], 0, 0, 0);
            acc2[nt] = __builtin_amdgcn_mfma_f32_16x16x32_bf16(ah2[c], wl, acc2[nt], 0, 0, 0);
        }
    }
    #pragma unroll
    for (int nt = 0; nt < 8; ++nt) {
        int col  = nt * 16 + rlo;
        float bb = bias2[col];
        float sv = g[col] * rsqrtf(v[col] + 1e-5f);
        float tv = be[col] - m[col] * sv;
        #pragma unroll
        for (int jj = 0; jj < 4; ++jj) {
            int lr = wid * 16 + kgrp * 4 + jj;
            float val = fmaxf(acc2[nt][jj] + bb, 0.f) * sv + tv;
            short h = f2bf(val);
            h1hi[lr * LDW + col] = h;
            h1lo[lr * LDW + col] = f2bf(val - bf2f(h));
        }
    }
    __syncthreads();

    bf16x8 ah3[4], al3[4];
    #pragma unroll
    for (int c = 0; c < 4; ++c) {
        ah3[c] = *(bf16x8*)&h1hi[lr2 * LDW + c * 32 + kgrp * 8];
        al3[c] = *(bf16x8*)&h1lo[lr2 * LDW + c * 32 + kgrp * 8];
    }
    f32x4 acc3[8];
    #pragma unroll
    for (int i = 0; i < 8; ++i) acc3[i] = (f32x4)0.0f;
    #pragma unroll
    for (int c = 0; c < 4; ++c) {
        #pragma unroll
        for (int nt = 0; nt < 8; ++nt) {
            int fi = ((c * 8) + nt) * 64 + lane;
            bf16x8 wh = Plv[fi];
            bf16x8 wl = Plv[T + fi];
            acc3[nt] = __builtin_amdgcn_mfma_f32_16x16x32_bf16(ah3[c], wh, acc3[nt], 0, 0, 0);
            acc3[nt] = __builtin_amdgcn_mfma_f32_16x16x32_bf16(al3[c], wh, acc3[nt], 0, 0, 0);
            acc3[nt] = __builtin_amdgcn_mfma_f32_16x16x32_bf16(ah3[c], wl, acc3[nt], 0, 0, 0);
        }
    }
    float p0 = 0, p1 = 0, p2 = 0, p3 = 0;
    #pragma unroll
    for (int nt = 0; nt < 8; ++nt) {
        int col  = nt * 16 + rlo;
        float bb = bl[col];
        float wv = Wf[col];
        p0 += fmaxf(acc3[nt][0] + bb, 0.f) * wv;
        p1 += fmaxf(acc3[nt][1] + bb, 0.f) * wv;
        p2 += fmaxf(acc3[nt][2] + bb, 0.f) * wv;
        p3 += fmaxf(acc3[nt][3] + bb, 0.f) * wv;
    }
    #pragma unroll
    for (int o = 1; o < 16; o <<= 1) {
        p0 += __shfl_xor(p0, o);
        p1 += __shfl_xor(p1, o);
        p2 += __shfl_xor(p2, o);
        p3 += __shfl_xor(p3, o);
    }
    if (rlo == 0) {
        int rbase = blockIdx.x * 64 + wid * 16 + kgrp * 4;
        float bfv = bf[0];
        if (rbase + 0 < M) out[rbase + 0] = p0 + bfv;
        if (rbase + 1 < M) out[rbase + 1] = p1 + bfv;
        if (rbase + 2 < M) out[rbase + 2] = p2 + bfv;
        if (rbase + 3 < M) out[rbase + 3] = p3 + bfv;
    }
}

// ---------------------------------------------------------------------------
extern "C" void kernel_launch(void* const* d_in, const int* in_sizes, int n_in,
                              void* d_out, int out_size, void* d_ws, size_t ws_size,
                              hipStream_t stream) {
    const float* x    = (const float*)d_in[0];
    const int*   eidx = (const int*)d_in[1];
    const float* eps1 = (const float*)d_in[2];
    const float* W1a  = (const float*)d_in[3];
    const float* b1a  = (const float*)d_in[4];
    const float* W1b  = (const float*)d_in[5];
    const float* b1b  = (const float*)d_in[6];
    const float* g1   = (const float*)d_in[7];
    const float* be1  = (const float*)d_in[8];
    const float* m1   = (const float*)d_in[9];
    const float* v1   = (const float*)d_in[10];
    const float* eps2 = (const float*)d_in[11];
    const float* W2a  = (const float*)d_in[12];
    const float* b2a  = (const float*)d_in[13];
    const float* g2   = (const float*)d_in[14];
    const float* be2  = (const float*)d_in[15];
    const float* m2   = (const float*)d_in[16];
    const float* v2   = (const float*)d_in[17];
    const float* eps3 = (const float*)d_in[18];
    const float* W3a  = (const float*)d_in[19];
    const float* b3a  = (const float*)d_in[20];
    const float* W3b  = (const float*)d_in[21];
    const float* b3b  = (const float*)d_in[22];
    const float* g3   = (const float*)d_in[23];
    const float* be3  = (const float*)d_in[24];
    const float* m3   = (const float*)d_in[25];
    const float* v3   = (const float*)d_in[26];
    const float* Wl   = (const float*)d_in[27];
    const float* bl   = (const float*)d_in[28];
    const float* Wf   = (const float*)d_in[29];
    const float* bfp  = (const float*)d_in[30];

    char* ws = (char*)d_ws;
    size_t off = 0;
    auto alloc = [&](size_t bytes) -> void* {
        off = (off + 255) & ~(size_t)255;
        void* p = ws + off;
        off += bytes;
        return p;
    };

    float*          bufA = (float*)alloc((size_t)NN * 128 * 4);
    float*          bufB = (float*)alloc((size_t)NN * 128 * 4);
    unsigned short* hb   = (unsigned short*)alloc((size_t)NN * 128 * 2);
    int*   offs   = (int*)alloc((size_t)(NN + 1) * 4);
    int*   esrc   = (int*)alloc((size_t)NE * 4);
    int*   bcnt   = (int*)alloc((size_t)NBUCK * 4);
    int*   bbase  = (int*)alloc((size_t)(NBUCK + 1) * 4);
    int*   pbase  = (int*)alloc((size_t)NBLK * NBUCK * 4);
    short* P1a    = (short*)alloc((size_t)2 * DIN * HID * 2);
    short* P1b    = (short*)alloc((size_t)2 * HID * HID * 2);
    short* P2a    = (short*)alloc((size_t)2 * HID * HID * 2);
    short* P3a    = (short*)alloc((size_t)2 * HID * HID * 2);
    short* P3b    = (short*)alloc((size_t)2 * HID * HID * 2);
    short* Pl     = (short*)alloc((size_t)2 * HID * HID * 2);
    // tmp edge pairs (12.8 MB) alias bufA: only live during CSR build, which
    // completes before aggb writes bufA.
    int2*  tmp    = (int2*)bufA;

    const int GRID_G    = (NN + 127) / 128;         // gemm_bn, 128 rows
    const int GRID_F    = (NN + 63) / 64;           // fused, 64 rows
    const int GRID_A64  = (NN + 31) / 32;           // aggb<64>: 32 nodes/block
    const int GRID_A128 = (NN + 15) / 16;           // aggb<128>: 16 nodes/block

    // ---- CSR build (2-level counting sort)
    hipMemsetAsync(bcnt, 0, (size_t)NBUCK * 4, stream);
    bhist_kernel<<<NBLK, 256, 0, stream>>>(eidx, bcnt, pbase);
    bscan_kernel<<<1, 256, 0, stream>>>(bcnt, bbase, offs);
    part_kernel<<<NBLK, 256, 0, stream>>>(eidx, bbase, pbase, tmp);
    bsort_kernel<<<NBUCK, 512, 0, stream>>>(bbase, tmp, offs, esrc);

    // ---- pack weights + bf16 x
    {
        dim3 grid(8, 6);
        packall_kernel<<<grid, 256, 0, stream>>>(W1a, W1b, W2a, W3a, W3b, Wl,
                                                 P1a, P1b, P2a, P3a, P3b, Pl);
    }
    cvt_kernel<<<(NN * DIN / 8 + 255) / 256, 256, 0, stream>>>(x, hb);

    // ---- layer 1 (agg -> fused W1a+W1b+BN)
    aggb_kernel<64><<<GRID_A64, 256, 0, stream>>>(x, hb, offs, esrc, eps1, bufA);
    fused2_kernel<64><<<GRID_F, 256, 0, stream>>>(bufA, P1a, b1a, P1b, b1b,
                                                  g1, be1, m1, v1, bufB, hb, NN);
    // ---- layer 2 (agg -> single GEMM+BN)
    aggb_kernel<128><<<GRID_A128, 256, 0, stream>>>(bufB, hb, offs, esrc, eps2, bufA);
    gemm_bn_kernel<<<GRID_G, 512, 0, stream>>>(bufA, P2a, b2a, g2, be2, m2, v2,
                                               bufB, hb, NN);
    // ---- layer 3 + head (agg -> fused W3a+W3b+BN+Wl+Wf)
    aggb_kernel<128><<<GRID_A128, 256, 0, stream>>>(bufB, hb, offs, esrc, eps3, bufA);
    fused3_kernel<<<GRID_F, 256, 0, stream>>>(bufA, P3a, b3a, P3b, b3b,
                                              g3, be3, m3, v3, Pl, bl, Wf, bfp,
                                              (float*)d_out, NN);
}